// Round 9
// baseline (528.710 us; speedup 1.0000x reference)
//
#include <hip/hip_runtime.h>
#include <hip/hip_bf16.h>
#include <hip/hip_fp16.h>

// I/O f32. Internal: bf16 MFMA GEMMs, f16 value/off/aw + packed-f16 sampling,
// bf16 residual path (threshold 9.9e-2 budgets low-precision internals).
// Levels (100,100),(50,50),(25,25),(13,13),(7,7); offsets 0,10000,12500,13125,13294
#define LTOT 13343
#define NLQ  26686
// fixed workspace byte offsets (used inside EPI7 epilogue)
#define WS_VALB 27326464
#define WS_R    122969088
#define WS_AW   (WS_R + 17079040)
#define WS_REF  (WS_R + 25618560)

typedef __attribute__((ext_vector_type(8))) short bf16x8;
typedef __attribute__((ext_vector_type(4))) float f32x4;
typedef _Float16 f16x2 __attribute__((ext_vector_type(2)));

__device__ __forceinline__ short f2bs(float x) {
  __hip_bfloat16 h = __float2bfloat16(x);
  return __builtin_bit_cast(short, h);
}
__device__ __forceinline__ float b2f(__hip_bfloat16 x) { return __bfloat162float(x); }
__device__ __forceinline__ unsigned short f2bu(float x) {
  return __builtin_bit_cast(unsigned short, __float2bfloat16(x));
}

// async global->LDS 16B per lane; LDS dst must be wave-uniform base (+lane*16)
__device__ __forceinline__ void gld16(const void* g, void* l) {
  __builtin_amdgcn_global_load_lds(
      (const __attribute__((address_space(1))) void*)g,
      (__attribute__((address_space(3))) void*)l, 16, 0, 0);
}

// ---------------------------------------------------------------------------
// MFMA GEMM: out = epi(A(bf16) @ W^T + bias)
// MT=128: 128x128 tile, 4 waves 64x64; MT=64: 64x128 tile, 4 waves 64x32.
// EPI9: 64x256 tile (4 waves 64x64 cols, JF=4) so a block owns full 256-col
//       rows -> fused bias + residual + bf16-round + row-LayerNorm epilogue.
// FAST path (AMODE0/WMODE0): BK=64 double-panel staging, one barrier pair per
// 64-K. LDS: MT128 32KB, MT64 24KB, EPI9 40KB.
// EPI: 0 bias->f32 rowmap | 1 bias+sigmoid->f32 | 2 bias+relu->bf16 rowmap
//      3 atomicAdd f32 | 4 bias->f32 NCHW | 6 bias->bf16 rowmap
//      7 fused projection (val f16|off f16|aw f16|ref sigmoid f32)
//      8 bias + residual(bf16) -> bf16 rowmap
//      9 bias + residual(bf16) -> bf16-round -> LayerNorm(row,256) -> bf16
// ---------------------------------------------------------------------------
template<int MT, int AMODE, int EPI, int WMODE>
__global__ __launch_bounds__(256) void mgemm_k(
    const __hip_bfloat16* __restrict__ A, const void* __restrict__ Wv,
    const float* __restrict__ bias, void* __restrict__ outv,
    const __hip_bfloat16* __restrict__ resid,
    const float* __restrict__ lng, const float* __restrict__ lnb,
    int M, int Nc, int K, int k_len,
    int A_HW, int A_L, int A_off,
    int O_HW, int O_L, int O_off)
{
  constexpr int NT = (EPI == 9) ? 256 : 128;
  constexpr int JF = (MT == 128 || EPI == 9) ? 4 : 2;
  constexpr bool FAST = (AMODE == 0 && WMODE == 0);
  constexpr int AK = FAST ? 64 : 32;
  constexpr int PA = MT * 32;
  constexpr int PB = NT * 32;
  __shared__ __hip_bfloat16 ldsA[MT * AK];
  __shared__ __hip_bfloat16 ldsB[NT * AK];
  const int t = threadIdx.x;
  const int bm = blockIdx.x * MT, bn = blockIdx.y * NT;
  const int k0 = blockIdx.z * k_len;

  const int sl = t & 63;
  const int mloc = sl & 15;
  const int kbase = (sl >> 4) * 8;
  const int s0 = t >> 6;

  const int r0 = bm + s0 * 16 + mloc, r1 = r0 + 64;
  const int nc0 = bn + s0 * 16 + mloc, nc1 = nc0 + 64;
  const int nc2 = nc0 + 128, nc3 = nc0 + 192;

  const __hip_bfloat16 *ap0 = A, *ap1 = A;
  bool av0 = false, av1 = false;
  int g0n=0, g0h=0, g0w=0, g1n=0, g1h=0, g1w=0;
  if (AMODE == 0) {
    if (r0 < M) { int nn = r0 / A_HW, p = r0 - nn * A_HW;
      ap0 = A + (size_t)(nn * A_L + A_off + p) * K + kbase; av0 = true; }
    if (MT == 128 && r1 < M) { int nn = r1 / A_HW, p = r1 - nn * A_HW;
      ap1 = A + (size_t)(nn * A_L + A_off + p) * K + kbase; av1 = true; }
  } else {
    if (r0 < M) { g0n = r0 / 49; int p = r0 - g0n * 49; g0h = p / 7; g0w = p - g0h * 7; av0 = true; }
    if (r1 < M) { g1n = r1 / 49; int p = r1 - g1n * 49; g1h = p / 7; g1w = p - g1h * 7; av1 = true; }
  }
  const bool wv0 = nc0 < Nc, wv1 = nc1 < Nc;
  const bool wv2 = (EPI == 9) && (nc2 < Nc), wv3 = (EPI == 9) && (nc3 < Nc);
  const __hip_bfloat16 *wb0 = (const __hip_bfloat16*)Wv, *wb1 = wb0, *wb2 = wb0, *wb3 = wb0;
  const float *wf0 = (const float*)Wv, *wf1 = wf0;
  if (WMODE == 0) {
    if (wv0) wb0 = (const __hip_bfloat16*)Wv + (size_t)nc0 * K + kbase;
    if (wv1) wb1 = (const __hip_bfloat16*)Wv + (size_t)nc1 * K + kbase;
    if (wv2) wb2 = (const __hip_bfloat16*)Wv + (size_t)nc2 * K + kbase;
    if (wv3) wb3 = (const __hip_bfloat16*)Wv + (size_t)nc3 * K + kbase;
  } else {
    if (wv0) wf0 = (const float*)Wv + (size_t)nc0 * 9216;
    if (wv1) wf1 = (const float*)Wv + (size_t)nc1 * 9216;
  }

  __hip_bfloat16* lbA0 = ldsA + s0 * 512;
  __hip_bfloat16* lbA1 = lbA0 + 2048;
  __hip_bfloat16* lbB0 = ldsB + s0 * 512;
  __hip_bfloat16* lbB1 = lbB0 + 2048;
  __hip_bfloat16* lbB2 = lbB0 + 4096;
  __hip_bfloat16* lbB3 = lbB0 + 6144;
  __hip_bfloat16* lwA0 = ldsA + s0 * 512 + sl * 8;
  __hip_bfloat16* lwA1 = lwA0 + 2048;
  __hip_bfloat16* lwB0 = ldsB + s0 * 512 + sl * 8;
  __hip_bfloat16* lwB1 = lwB0 + 2048;

  const int lane = t & 63, wv_ = t >> 6;
  const __hip_bfloat16 *rA, *rB;
  int wmR, colbase;
  if (MT == 128) {
    int wm = wv_ >> 1, wn = wv_ & 1;
    rA = ldsA + wm * 2048 + lane * 8;
    rB = ldsB + wn * 2048 + lane * 8;
    wmR = wm * 64;
    colbase = bn + wn * 64;
  } else if (EPI == 9) {
    rA = ldsA + lane * 8;
    rB = ldsB + wv_ * 2048 + lane * 8;
    wmR = 0;
    colbase = bn + wv_ * 64;
  } else {
    rA = ldsA + lane * 8;
    rB = ldsB + wv_ * 1024 + lane * 8;
    wmR = 0;
    colbase = bn + wv_ * 32;
  }

  f32x4 acc[4][JF] = {};

  if (FAST) {
    for (int kt = k0; kt < k0 + k_len; kt += 64) {
      if (av0) { gld16(ap0 + kt, lbA0); gld16(ap0 + kt + 32, lbA0 + PA); }
      if (MT == 128) {
        if (av1) { gld16(ap1 + kt, lbA1); gld16(ap1 + kt + 32, lbA1 + PA); }
      }
      if (wv0) { gld16(wb0 + kt, lbB0); gld16(wb0 + kt + 32, lbB0 + PB); }
      if (wv1) { gld16(wb1 + kt, lbB1); gld16(wb1 + kt + 32, lbB1 + PB); }
      if (EPI == 9) {
        if (wv2) { gld16(wb2 + kt, lbB2); gld16(wb2 + kt + 32, lbB2 + PB); }
        if (wv3) { gld16(wb3 + kt, lbB3); gld16(wb3 + kt + 32, lbB3 + PB); }
      }
      __syncthreads();
#pragma unroll
      for (int h = 0; h < 2; h++) {
        bf16x8 af[4], bfr[JF];
#pragma unroll
        for (int i = 0; i < 4; i++) af[i] = *(const bf16x8*)(rA + h * PA + i * 512);
#pragma unroll
        for (int j = 0; j < JF; j++) bfr[j] = *(const bf16x8*)(rB + h * PB + j * 512);
#pragma unroll
        for (int i = 0; i < 4; i++)
#pragma unroll
          for (int j = 0; j < JF; j++)
            acc[i][j] = __builtin_amdgcn_mfma_f32_16x16x32_bf16(af[i], bfr[j], acc[i][j], 0, 0, 0);
      }
      __syncthreads();
    }
  } else {
    for (int kt = k0; kt < k0 + k_len; kt += 32) {
      {
        bf16x8 va0 = {}, va1 = {};
        int kp = kt + kbase;
        int rs = kp >> 10, c = kp & 1023;
        int rr = rs / 3, ss = rs - rr * 3;
        if (av0) { int ih = g0h*2-1+rr, iw = g0w*2-1+ss;
          if ((unsigned)ih < 13u && (unsigned)iw < 13u)
            va0 = *(const bf16x8*)(A + ((size_t)(g0n*169 + ih*13 + iw))*1024 + c); }
        if (av1) { int ih = g1h*2-1+rr, iw = g1w*2-1+ss;
          if ((unsigned)ih < 13u && (unsigned)iw < 13u)
            va1 = *(const bf16x8*)(A + ((size_t)(g1n*169 + ih*13 + iw))*1024 + c); }
        *(bf16x8*)lwA0 = va0;  *(bf16x8*)lwA1 = va1;
      }
      {
        bf16x8 vb0 = {}, vb1 = {};
        int kp = kt + kbase;
        int rs = kp >> 10, c = kp & 1023;
        if (wv0) { const float* p = wf0 + (size_t)c * 9 + rs;
#pragma unroll
          for (int j = 0; j < 8; j++) vb0[j] = f2bs(p[j * 9]); }
        if (wv1) { const float* p = wf1 + (size_t)c * 9 + rs;
#pragma unroll
          for (int j = 0; j < 8; j++) vb1[j] = f2bs(p[j * 9]); }
        *(bf16x8*)lwB0 = vb0;  *(bf16x8*)lwB1 = vb1;
      }
      __syncthreads();
      bf16x8 af[4], bfr[JF];
#pragma unroll
      for (int i = 0; i < 4; i++) af[i] = *(const bf16x8*)(rA + i * 512);
#pragma unroll
      for (int j = 0; j < JF; j++) bfr[j] = *(const bf16x8*)(rB + j * 512);
#pragma unroll
      for (int i = 0; i < 4; i++)
#pragma unroll
        for (int j = 0; j < JF; j++)
          acc[i][j] = __builtin_amdgcn_mfma_f32_16x16x32_bf16(af[i], bfr[j], acc[i][j], 0, 0, 0);
      __syncthreads();
    }
  }

  // epilogue: C/D map col=lane&15, row=(lane>>4)*4+reg
  const int quad = lane >> 4, nl = lane & 15;

  if constexpr (EPI == 9) {
    // fused bias + residual + bf16-round + row LayerNorm over Nc=256.
    // reduction scratch in ldsB (safe: K-loop ended on __syncthreads).
    float* red  = (float*)ldsB;          // [64 rows] stride 9: {sum, sumsq} x 4 waves
    float* redm = (float*)ldsB + 600;    // [64 rows] x {mean, rstd}
    float bv9[4], gj[4], bj[4]; int cj9[4];
#pragma unroll
    for (int j = 0; j < 4; j++) {
      cj9[j] = colbase + j * 16 + nl;
      bv9[j] = bias[cj9[j]];
      gj[j]  = lng[cj9[j]];
      bj[j]  = lnb[cj9[j]];
    }
#pragma unroll
    for (int i = 0; i < 4; i++) {
#pragma unroll
      for (int r = 0; r < 4; r++) {
        int row64 = i * 16 + quad * 4 + r;
        int m = bm + row64;
        if (m < M) {
          int n = m / O_HW, p = m - n * O_HW;
          size_t orow = (size_t)(n * O_L + O_off + p);
#pragma unroll
          for (int j = 0; j < 4; j++) {
            float v = acc[i][j][r] + bv9[j] + b2f(resid[orow * Nc + cj9[j]]);
            acc[i][j][r] = b2f(__float2bfloat16(v));  // round first, stats on rounded
          }
        } else {
#pragma unroll
          for (int j = 0; j < 4; j++) acc[i][j][r] = 0.f;
        }
        float s  = acc[i][0][r] + acc[i][1][r] + acc[i][2][r] + acc[i][3][r];
        float s2 = acc[i][0][r]*acc[i][0][r] + acc[i][1][r]*acc[i][1][r]
                 + acc[i][2][r]*acc[i][2][r] + acc[i][3][r]*acc[i][3][r];
        // reduce across the 16-lane col group (quad fixed within group)
        s  += __shfl_xor(s, 1, 64);  s2 += __shfl_xor(s2, 1, 64);
        s  += __shfl_xor(s, 2, 64);  s2 += __shfl_xor(s2, 2, 64);
        s  += __shfl_xor(s, 4, 64);  s2 += __shfl_xor(s2, 4, 64);
        s  += __shfl_xor(s, 8, 64);  s2 += __shfl_xor(s2, 8, 64);
        if (nl == 0) { red[row64 * 9 + wv_ * 2] = s; red[row64 * 9 + wv_ * 2 + 1] = s2; }
      }
    }
    __syncthreads();
    if (t < 64) {
      float S = 0.f, S2 = 0.f;
#pragma unroll
      for (int w = 0; w < 4; w++) { S += red[t * 9 + w * 2]; S2 += red[t * 9 + w * 2 + 1]; }
      float mean = S * (1.f / 256.f);
      float var  = S2 * (1.f / 256.f) - mean * mean;
      redm[t * 2]     = mean;
      redm[t * 2 + 1] = rsqrtf(var + 1e-5f);
    }
    __syncthreads();
#pragma unroll
    for (int i = 0; i < 4; i++) {
#pragma unroll
      for (int r = 0; r < 4; r++) {
        int row64 = i * 16 + quad * 4 + r;
        int m = bm + row64;
        if (m >= M) continue;
        float mean = redm[row64 * 2], rstd = redm[row64 * 2 + 1];
        int n = m / O_HW, p = m - n * O_HW;
        size_t orow = (size_t)(n * O_L + O_off + p);
#pragma unroll
        for (int j = 0; j < 4; j++) {
          float o = (acc[i][j][r] - mean) * rstd * gj[j] + bj[j];
          ((__hip_bfloat16*)outv)[orow * Nc + cj9[j]] = __float2bfloat16(o);
        }
      }
    }
    return;
  }

  float bv[JF]; int cj[JF]; bool cv[JF];
#pragma unroll
  for (int j = 0; j < JF; j++) {
    cj[j] = colbase + j * 16 + nl;
    cv[j] = cj[j] < Nc;
    bv[j] = (EPI != 3 && cv[j]) ? bias[cj[j]] : 0.f;
  }
#pragma unroll
  for (int i = 0; i < 4; i++) {
#pragma unroll
    for (int r = 0; r < 4; r++) {
      int m = bm + wmR + i * 16 + quad * 4 + r;
      if (m >= M) continue;
      int n = m / O_HW, p = m - n * O_HW;
      size_t orow = (size_t)(n * O_L + O_off + p);
#pragma unroll
      for (int j = 0; j < JF; j++) {
        if (!cv[j]) continue;
        float v = acc[i][j][r] + bv[j];
        if (EPI == 1) v = 1.f / (1.f + expf(-v));
        if (EPI == 2) v = fmaxf(v, 0.f);
        if (EPI == 0 || EPI == 1) ((float*)outv)[orow * Nc + cj[j]] = v;
        else if (EPI == 2 || EPI == 6) ((__hip_bfloat16*)outv)[orow * Nc + cj[j]] = __float2bfloat16(v);
        else if (EPI == 3) atomicAdd((float*)outv + orow * Nc + cj[j], acc[i][j][r]);
        else if (EPI == 8) {
          float rv = b2f(resid[orow * Nc + cj[j]]);
          ((__hip_bfloat16*)outv)[orow * Nc + cj[j]] = __float2bfloat16(v + rv);
        }
        else if (EPI == 7) {
          char* base = (char*)outv;
          int q = m, c = cj[j];
          if (c < 256)
            ((_Float16*)(base + WS_VALB))[(size_t)q * 256 + c] = (_Float16)v;
          else if (c < 576)
            ((_Float16*)(base + WS_R))[(size_t)q * 320 + (c - 256)] = (_Float16)v;
          else if (c < 736)
            ((_Float16*)(base + WS_AW))[(size_t)q * 160 + (c - 576)] = (_Float16)v;
          else {
            float sv = 1.f / (1.f + expf(-v));
            ((float*)(base + WS_REF))[(size_t)q * 10 + (c - 736)] = sv;
          }
        }
        else ((float*)outv)[((size_t)n * Nc + cj[j]) * O_HW + p] = v;
      }
    }
  }
}

// ---------------------------------------------------------------------------
// fused FFN v2: out = LN2(h1 + relu(h1@W1^T + b1)@W2^T + b2). Bit-identical
// math to v1/split path (same K order, same bf16 round points) -- only the
// M-tiling changed. [R7: 64-row/417-block/64KB version was latency-starved:
// grid 1.6 blk/CU, occ 17%, MfmaUtil 13%, 81us.] v2: 32 rows/block ->
// 834 blocks, LDS 40KB (A-res 16K + mid 8K + Wpanel 16K) -> 4 blk/CU
// capacity, ~3.3 resident -> ~13 waves/CU. acc 48 f32 -> ~90 VGPR.
// W re-read doubles (834MB, L2-resident, <19 TB/s demand -- OK).
// ---------------------------------------------------------------------------
__global__ __launch_bounds__(256) void ffn_k(
    const __hip_bfloat16* __restrict__ h1, const __hip_bfloat16* __restrict__ W1,
    const float* __restrict__ b1, const __hip_bfloat16* __restrict__ W2,
    const float* __restrict__ b2, const float* __restrict__ lng,
    const float* __restrict__ lnb, __hip_bfloat16* __restrict__ out)
{
  __shared__ char smem[40960];
  __hip_bfloat16* ldsA = (__hip_bfloat16*)smem;             // 16KB: 32 rows x 256 K (frag layout)
  __hip_bfloat16* ldsM = (__hip_bfloat16*)(smem + 16384);   // 8KB: 32 x 128 mid (frag layout)
  __hip_bfloat16* ldsW = (__hip_bfloat16*)(smem + 24576);   // 16KB: 128x64 W panel
  const int t = threadIdx.x;
  const int bm = blockIdx.x * 32;
  const int sl = t & 63, mloc = sl & 15, kbase = (sl >> 4) * 8, s0 = t >> 6;
  const int lane = t & 63, wv_ = t >> 6;
  const int quad = lane >> 4, nl = lane & 15;

  // stage A = h1 rows [bm, bm+32) x K=256 resident, frag layout:
  // elem(row,k) = (k>>6)*2048 + ((k>>5)&1)*1024 + (row>>4)*512
  //             + ((k>>3)&3)*128 + (row&15)*8 + (k&7)
  {
    const int r0a = bm + (s0 & 1) * 16 + mloc;
    if (r0a < NLQ) {
      const __hip_bfloat16* ap = h1 + (size_t)r0a * 256 + (s0 >> 1) * 32 + kbase;
#pragma unroll
      for (int p = 0; p < 4; p++)
        gld16(ap + p * 64, ldsA + p * 2048 + s0 * 512);
    }
  }

  const int ca = s0 * 16 + mloc;   // staging col within a 128-col W group
  const __hip_bfloat16* rA = ldsA + lane * 8;
  const __hip_bfloat16* rM = ldsM + lane * 8;
  const __hip_bfloat16* rB = ldsW + wv_ * 1024 + lane * 8;

  f32x4 acc2[2][4] = {};

  for (int c = 0; c < 8; c++) {
    // ---- GEMM1: mid[32x128] = A @ W1[c*128 .. +127]^T  (K=256) ----
    f32x4 acc1[2][2] = {};
    const __hip_bfloat16* wp0 = W1 + (size_t)(c * 128 + ca) * 256 + kbase;
    const __hip_bfloat16* wp1 = wp0 + (size_t)64 * 256;
    for (int kt = 0; kt < 256; kt += 64) {
      gld16(wp0 + kt,      ldsW + s0 * 512);
      gld16(wp0 + kt + 32, ldsW + s0 * 512 + 4096);
      gld16(wp1 + kt,      ldsW + s0 * 512 + 2048);
      gld16(wp1 + kt + 32, ldsW + s0 * 512 + 2048 + 4096);
      __syncthreads();
      const int p = kt >> 6;
#pragma unroll
      for (int h = 0; h < 2; h++) {
        bf16x8 af[2], bfr[2];
#pragma unroll
        for (int i = 0; i < 2; i++) af[i] = *(const bf16x8*)(rA + p * 2048 + h * 1024 + i * 512);
#pragma unroll
        for (int j = 0; j < 2; j++) bfr[j] = *(const bf16x8*)(rB + h * 4096 + j * 512);
#pragma unroll
        for (int i = 0; i < 2; i++)
#pragma unroll
          for (int j = 0; j < 2; j++)
            acc1[i][j] = __builtin_amdgcn_mfma_f32_16x16x32_bf16(af[i], bfr[j], acc1[i][j], 0, 0, 0);
      }
      __syncthreads();
    }
    // bias + relu + bf16-round -> ldsM in frag layout (rows 32)
#pragma unroll
    for (int j = 0; j < 2; j++) {
      int kc = wv_ * 32 + j * 16 + nl;
      float bb = b1[c * 128 + kc];
      int ka = (kc >> 6) * 2048 + ((kc >> 5) & 1) * 1024 + ((kc >> 3) & 3) * 128 + (kc & 7);
#pragma unroll
      for (int i = 0; i < 2; i++)
#pragma unroll
        for (int r = 0; r < 4; r++) {
          float v = fmaxf(acc1[i][j][r] + bb, 0.f);
          ldsM[ka + i * 512 + (quad * 4 + r) * 8] = __float2bfloat16(v);
        }
    }
    // ---- GEMM2: acc2 += mid @ W2[:, c*128 .. +127]^T  (K-slice 128) ----
    for (int kt2 = 0; kt2 < 128; kt2 += 64) {
      const int p2 = kt2 >> 6;
#pragma unroll
      for (int hc = 0; hc < 2; hc++) {
        const __hip_bfloat16* wq0 = W2 + (size_t)(hc * 128 + ca) * 1024 + c * 128 + kt2 + kbase;
        const __hip_bfloat16* wq1 = wq0 + (size_t)64 * 1024;
        gld16(wq0,      ldsW + s0 * 512);
        gld16(wq0 + 32, ldsW + s0 * 512 + 4096);
        gld16(wq1,      ldsW + s0 * 512 + 2048);
        gld16(wq1 + 32, ldsW + s0 * 512 + 2048 + 4096);
        __syncthreads();
#pragma unroll
        for (int h = 0; h < 2; h++) {
          bf16x8 mf[2], bfr[2];
#pragma unroll
          for (int i = 0; i < 2; i++) mf[i] = *(const bf16x8*)(rM + p2 * 2048 + h * 1024 + i * 512);
#pragma unroll
          for (int j = 0; j < 2; j++) bfr[j] = *(const bf16x8*)(rB + h * 4096 + j * 512);
#pragma unroll
          for (int i = 0; i < 2; i++)
#pragma unroll
            for (int j = 0; j < 2; j++)
              acc2[i][hc * 2 + j] = __builtin_amdgcn_mfma_f32_16x16x32_bf16(mf[i], bfr[j], acc2[i][hc * 2 + j], 0, 0, 0);
        }
        __syncthreads();
      }
    }
  }

  // ---- EPI9-style epilogue: bias + resid(from ldsA) + round + LN -> out ----
  float* red  = (float*)ldsM;          // [32 rows] stride 9: {sum,sumsq} x 4 waves
  float* redm = (float*)ldsM + 300;    // [32 rows] x {mean, rstd}
  float bv9[4], gj[4], bj[4]; int cj9[4];
#pragma unroll
  for (int j = 0; j < 4; j++) {
    int hc = j >> 1, jj = j & 1;
    cj9[j] = hc * 128 + wv_ * 32 + jj * 16 + nl;
    bv9[j] = b2[cj9[j]];
    gj[j]  = lng[cj9[j]];
    bj[j]  = lnb[cj9[j]];
  }
#pragma unroll
  for (int i = 0; i < 2; i++) {
#pragma unroll
    for (int r = 0; r < 4; r++) {
      int row32 = i * 16 + quad * 4 + r;
      int m = bm + row32;
      if (m < NLQ) {
#pragma unroll
        for (int j = 0; j < 4; j++) {
          int k = cj9[j];
          // resid from resident A copy (bit-identical to h1 global read)
          int la = (k >> 6) * 2048 + ((k >> 5) & 1) * 1024 + i * 512
                 + ((k >> 3) & 3) * 128 + (quad * 4 + r) * 8 + (k & 7);
          float rv = b2f(ldsA[la]);
          float v = acc2[i][j][r] + bv9[j] + rv;
          acc2[i][j][r] = b2f(__float2bfloat16(v));
        }
      } else {
#pragma unroll
        for (int j = 0; j < 4; j++) acc2[i][j][r] = 0.f;
      }
      float s  = acc2[i][0][r] + acc2[i][1][r] + acc2[i][2][r] + acc2[i][3][r];
      float s2 = acc2[i][0][r]*acc2[i][0][r] + acc2[i][1][r]*acc2[i][1][r]
               + acc2[i][2][r]*acc2[i][2][r] + acc2[i][3][r]*acc2[i][3][r];
      s  += __shfl_xor(s, 1, 64);  s2 += __shfl_xor(s2, 1, 64);
      s  += __shfl_xor(s, 2, 64);  s2 += __shfl_xor(s2, 2, 64);
      s  += __shfl_xor(s, 4, 64);  s2 += __shfl_xor(s2, 4, 64);
      s  += __shfl_xor(s, 8, 64);  s2 += __shfl_xor(s2, 8, 64);
      if (nl == 0) { red[row32 * 9 + wv_ * 2] = s; red[row32 * 9 + wv_ * 2 + 1] = s2; }
    }
  }
  __syncthreads();
  if (t < 32) {
    float S = 0.f, S2 = 0.f;
#pragma unroll
    for (int w = 0; w < 4; w++) { S += red[t * 9 + w * 2]; S2 += red[t * 9 + w * 2 + 1]; }
    float mean = S * (1.f / 256.f);
    float var  = S2 * (1.f / 256.f) - mean * mean;
    redm[t * 2]     = mean;
    redm[t * 2 + 1] = rsqrtf(var + 1e-5f);
  }
  __syncthreads();
#pragma unroll
  for (int i = 0; i < 2; i++) {
#pragma unroll
    for (int r = 0; r < 4; r++) {
      int row32 = i * 16 + quad * 4 + r;
      int m = bm + row32;
      if (m >= NLQ) continue;
      float mean = redm[row32 * 2], rstd = redm[row32 * 2 + 1];
#pragma unroll
      for (int j = 0; j < 4; j++) {
        float o = (acc2[i][j][r] - mean) * rstd * gj[j] + bj[j];
        out[(size_t)m * 256 + cj9[j]] = __float2bfloat16(o);
      }
    }
  }
}

// ---------------------------------------------------------------------------
// table-driven 3-job GEMM (MT=64, FAST, bf16 W):
// EPI0 (input convs -> f32 rowmap) + fused GroupNorm raw-stat atomics
// EPI4 (output convs -> f32 NCHW) with LDS-transposed coalesced stores
// WITHCOPY: blocks >= gend do the lvl1 h2b->out f32 transpose copy.
// WITHC4:   blocks >= gend do conv4 (3x3 s2 on xt3, K=9216 split 32 chunks,
//           pre-transposed bf16 W, atomicAdd f32 into src rowmap).
// ---------------------------------------------------------------------------
struct GJob {
  const __hip_bfloat16* A; const __hip_bfloat16* W;
  const float* bias; float* out;
  int M, Nc, K, A_HW, A_L, A_off, O_HW, O_L, O_off, base, nbx;
};
struct GJobs { GJob j[3]; };

template<int EPI, bool WITHCOPY, bool WITHC4>
__global__ __launch_bounds__(256) void mgemm3_k(GJobs tab, int gend,
    const __hip_bfloat16* __restrict__ cpsrc, float* __restrict__ cpdst,
    const __hip_bfloat16* __restrict__ c4A, const __hip_bfloat16* __restrict__ c4W,
    float* __restrict__ c4out, float* __restrict__ stats)
{
  __shared__ char smem[24576];
  __hip_bfloat16* ldsA = (__hip_bfloat16*)smem;            // 8 KB
  __hip_bfloat16* ldsB = (__hip_bfloat16*)(smem + 8192);   // 16 KB
  const int t = threadIdx.x;
  const int b = blockIdx.x;

  if (WITHCOPY && b >= gend) {
    // lvl1 copy-out: h2b rows [10000,12500) bf16 -> out (N,256,50,50) f32
    int bb = b - gend;
    float (*tile)[33] = (float(*)[33])smem;
    int p0 = (bb % 79) * 32; int r = bb / 79; int c0 = (r & 7) * 32; int n = r >> 3;
    int tx = t & 31, ty = t >> 5;
    for (int i = ty; i < 32; i += 8) {
      int p = p0 + i, c = c0 + tx;
      tile[tx][i] = (p < 2500) ? b2f(cpsrc[((size_t)(n * LTOT + 10000 + p)) * 256 + c]) : 0.f;
    }
    __syncthreads();
    for (int i = ty; i < 32; i += 8) {
      int c = c0 + i, p = p0 + tx;
      if (p < 2500) cpdst[((size_t)n * 256 + c) * 2500 + p] = tile[i][tx];
    }
    return;
  }

  if (WITHC4 && b >= gend) {
    // conv4: M=98 rows, Nc=256, K=9216 in 32 chunks of 288. 2x2x32 = 128 blocks.
    int cb = b - gend;
    int kz = cb >> 2, bx2 = cb & 1, by2 = (cb >> 1) & 1;
    int bm = bx2 * 64, bn = by2 * 128;
    int k0 = kz * 288;
    const int sl = t & 63, mloc = sl & 15, kbase = (sl >> 4) * 8, s0 = t >> 6;
    int r0 = bm + s0 * 16 + mloc;
    bool av0 = r0 < 98;
    int g0n = 0, g0h = 0, g0w = 0;
    if (av0) { g0n = r0 / 49; int p = r0 - g0n * 49; g0h = p / 7; g0w = p - g0h * 7; }
    int nc0 = bn + s0 * 16 + mloc, nc1 = nc0 + 64;
    const __hip_bfloat16* wb0 = c4W + (size_t)nc0 * 9216;
    const __hip_bfloat16* wb1 = c4W + (size_t)nc1 * 9216;
    __hip_bfloat16* lwA0 = ldsA + s0 * 512 + sl * 8;
    __hip_bfloat16* lwB0 = ldsB + s0 * 512 + sl * 8;
    __hip_bfloat16* lwB1 = lwB0 + 2048;
    const int lane = t & 63, wvw = t >> 6;
    const __hip_bfloat16* rA = ldsA + lane * 8;
    const __hip_bfloat16* rB = ldsB + wvw * 1024 + lane * 8;
    const int colbase = bn + wvw * 32;
    f32x4 acc[4][2] = {};
    for (int kt = k0; kt < k0 + 288; kt += 32) {
      int kp = kt + kbase;
      {
        bf16x8 va0 = {};
        int rs = kp >> 10, c = kp & 1023;
        int rr = rs / 3, ss = rs - rr * 3;
        if (av0) { int ih = g0h*2-1+rr, iw = g0w*2-1+ss;
          if ((unsigned)ih < 13u && (unsigned)iw < 13u)
            va0 = *(const bf16x8*)(c4A + ((size_t)(g0n*169 + ih*13 + iw))*1024 + c); }
        *(bf16x8*)lwA0 = va0;
      }
      *(bf16x8*)lwB0 = *(const bf16x8*)(wb0 + kp);
      *(bf16x8*)lwB1 = *(const bf16x8*)(wb1 + kp);
      __syncthreads();
      bf16x8 af[4], bfr[2];
#pragma unroll
      for (int i = 0; i < 4; i++) af[i] = *(const bf16x8*)(rA + i * 512);
#pragma unroll
      for (int j2 = 0; j2 < 2; j2++) bfr[j2] = *(const bf16x8*)(rB + j2 * 512);
#pragma unroll
      for (int i = 0; i < 4; i++)
#pragma unroll
        for (int j2 = 0; j2 < 2; j2++)
          acc[i][j2] = __builtin_amdgcn_mfma_f32_16x16x32_bf16(af[i], bfr[j2], acc[i][j2], 0, 0, 0);
      __syncthreads();
    }
    const int quad = lane >> 4, nl = lane & 15;
#pragma unroll
    for (int i = 0; i < 4; i++) {
#pragma unroll
      for (int r = 0; r < 4; r++) {
        int m = bm + i * 16 + quad * 4 + r;
        if (m >= 98) continue;
        int n = m / 49, p = m - n * 49;
        size_t orow = (size_t)(n * LTOT + 13294 + p);
#pragma unroll
        for (int j2 = 0; j2 < 2; j2++)
          atomicAdd(c4out + orow * 256 + colbase + j2 * 16 + nl, acc[i][j2][r]);
      }
    }
    return;
  }

  const int j = (b >= tab.j[1].base) + (b >= tab.j[2].base);
  const GJob J = tab.j[j];
  const int local = b - J.base;
  const int bx = local % J.nbx, by = local / J.nbx;
  const int bm = bx * 64, bn = by * 128;

  const int sl = t & 63, mloc = sl & 15, kbase = (sl >> 4) * 8, s0 = t >> 6;
  const int r0 = bm + s0 * 16 + mloc;
  const int nc0 = bn + s0 * 16 + mloc, nc1 = nc0 + 64;

  const __hip_bfloat16* ap0 = J.A; bool av0 = false;
  if (r0 < J.M) { int nn = r0 / J.A_HW, p = r0 - nn * J.A_HW;
    ap0 = J.A + (size_t)(nn * J.A_L + J.A_off + p) * J.K + kbase; av0 = true; }
  const bool wv0 = nc0 < J.Nc, wv1 = nc1 < J.Nc;
  const __hip_bfloat16 *wb0 = J.W, *wb1 = J.W;
  if (wv0) wb0 = J.W + (size_t)nc0 * J.K + kbase;
  if (wv1) wb1 = J.W + (size_t)nc1 * J.K + kbase;

  __hip_bfloat16* lbA0 = ldsA + s0 * 512;
  __hip_bfloat16* lbB0 = ldsB + s0 * 512;
  __hip_bfloat16* lbB1 = lbB0 + 2048;
  const int lane = t & 63, wv_ = t >> 6;
  const __hip_bfloat16* rA = ldsA + lane * 8;
  const __hip_bfloat16* rB = ldsB + wv_ * 1024 + lane * 8;
  const int colbase = bn + wv_ * 32;

  f32x4 acc[4][2] = {};
  for (int kt = 0; kt < J.K; kt += 64) {
    if (av0) { gld16(ap0 + kt, lbA0); gld16(ap0 + kt + 32, lbA0 + 2048); }
    if (wv0) { gld16(wb0 + kt, lbB0); gld16(wb0 + kt + 32, lbB0 + 4096); }
    if (wv1) { gld16(wb1 + kt, lbB1); gld16(wb1 + kt + 32, lbB1 + 4096); }
    __syncthreads();
#pragma unroll
    for (int h = 0; h < 2; h++) {
      bf16x8 af[4], bfr[2];
#pragma unroll
      for (int i = 0; i < 4; i++) af[i] = *(const bf16x8*)(rA + h * 2048 + i * 512);
#pragma unroll
      for (int j2 = 0; j2 < 2; j2++) bfr[j2] = *(const bf16x8*)(rB + h * 4096 + j2 * 512);
#pragma unroll
      for (int i = 0; i < 4; i++)
#pragma unroll
        for (int j2 = 0; j2 < 2; j2++)
          acc[i][j2] = __builtin_amdgcn_mfma_f32_16x16x32_bf16(af[i], bfr[j2], acc[i][j2], 0, 0, 0);
    }
    __syncthreads();
  }

  const int quad = lane >> 4, nl = lane & 15;
  float bv[2]; int cj[2];
#pragma unroll
  for (int j2 = 0; j2 < 2; j2++) {
    cj[j2] = colbase + j2 * 16 + nl;
    bv[j2] = J.bias[cj[j2]];   // all cols valid: job grids exactly cover Nc
  }

  if constexpr (EPI == 0) {
    // rowmap store + fused GroupNorm raw-stat accumulation (li = job idx).
    // stats on the EXACT stored f32 values; order-only difference vs 2-pass.
    float sA[2] = {0.f, 0.f}, qA[2] = {0.f, 0.f};   // n=0 sum / sumsq per j2
    float sB[2] = {0.f, 0.f}, qB[2] = {0.f, 0.f};   // n=1
#pragma unroll
    for (int i = 0; i < 4; i++) {
#pragma unroll
      for (int r = 0; r < 4; r++) {
        int m = bm + i * 16 + quad * 4 + r;
        if (m >= J.M) continue;
        int n = m / J.O_HW, p = m - n * J.O_HW;
        size_t orow = (size_t)(n * J.O_L + J.O_off + p);
#pragma unroll
        for (int j2 = 0; j2 < 2; j2++) {
          float v = acc[i][j2][r] + bv[j2];
          J.out[orow * J.Nc + cj[j2]] = v;
          if (n == 0) { sA[j2] += v; qA[j2] += v * v; }
          else        { sB[j2] += v; qB[j2] += v * v; }
        }
      }
    }
    // reduce over all lanes sharing the same channel-group (nl bit3):
    // nl bits 0-2 (masks 1,2,4) and quad bits 4-5 (masks 16,32). Skip bit 3.
    // [R5 BUG: (8<<d) gave masks 64/128 -> self-wrap -> quarter-sampled stats]
    const int msks[5] = {1, 2, 4, 16, 32};
#pragma unroll
    for (int j2 = 0; j2 < 2; j2++) {
      float s0v = sA[j2], q0v = qA[j2], s1v = sB[j2], q1v = qB[j2];
#pragma unroll
      for (int d = 0; d < 5; d++) {
        int msk = msks[d];
        s0v += __shfl_xor(s0v, msk, 64);  q0v += __shfl_xor(q0v, msk, 64);
        s1v += __shfl_xor(s1v, msk, 64);  q1v += __shfl_xor(q1v, msk, 64);
      }
      if (lane == 0 || lane == 8) {
        int g = cj[j2] >> 3;
        if (s0v != 0.f || q0v != 0.f) {
          int si = (j * 2 + 0) * 32 + g;
          atomicAdd(&stats[si * 2], s0v);  atomicAdd(&stats[si * 2 + 1], q0v);
        }
        if (s1v != 0.f || q1v != 0.f) {
          int si = (j * 2 + 1) * 32 + g;
          atomicAdd(&stats[si * 2], s1v);  atomicAdd(&stats[si * 2 + 1], q1v);
        }
      }
    }
    return;
  }

  // EPI4: NCHW f32 output, coalesced via LDS transpose (64 p x 64 c halves).
  float* tbuf = (float*)smem;   // [64][65] f32 = 16.6 KB (aliases ldsA/ldsB, free now)
#pragma unroll
  for (int h2 = 0; h2 < 2; h2++) {
    __syncthreads();
    if ((wv_ >> 1) == h2) {
      int cbase = (wv_ & 1) * 32;
#pragma unroll
      for (int i = 0; i < 4; i++)
#pragma unroll
        for (int r = 0; r < 4; r++) {
          int pl = i * 16 + quad * 4 + r;
#pragma unroll
          for (int j2 = 0; j2 < 2; j2++)
            tbuf[pl * 65 + cbase + j2 * 16 + nl] = acc[i][j2][r] + bv[j2];
        }
    }
    __syncthreads();
#pragma unroll
    for (int kk = 0; kk < 16; kk++) {
      int idx = kk * 256 + t;
      int cl = idx >> 6, pl = idx & 63;       // wave -> channel, lanes -> p (contig)
      int m = bm + pl;
      if (m < J.M) {
        int n = m / J.O_HW, p = m - n * J.O_HW;
        J.out[((size_t)n * J.Nc + (bn + h2 * 64 + cl)) * J.O_HW + p] = tbuf[pl * 65 + cl];
      }
    }
  }
}

// flat bulk weight conversion + bias concat + stats zero + conv4 bias init
// + Wc4 pre-transpose to bf16 kp-order: wt4[nc][rs*1024+c] = Wc4[nc][c*9+rs]
// 1-D grid sized to exact work (7504 blocks) -- no empty-slice blocks.
#define CVT_T13 1632768
struct CvtEnt { const float* s; __hip_bfloat16* d; int n; int base; };
struct CvtTab { CvtEnt e[13]; };
__global__ __launch_bounds__(256) void cvt_weights_k(CvtTab tab,
    const float* __restrict__ bv, const float* __restrict__ bo,
    const float* __restrict__ ba, const float* __restrict__ br,
    float* __restrict__ catbias, float* __restrict__ stats,
    float* __restrict__ src, const float* __restrict__ bc4,
    const float* __restrict__ Wc4f, __hip_bfloat16* __restrict__ wt4)
{
  int i = blockIdx.x * 256 + threadIdx.x;
  if (i < CVT_T13) {
#pragma unroll
    for (int j = 12; j >= 0; j--) {
      if (i >= tab.e[j].base) {
        int k = i - tab.e[j].base;
        tab.e[j].d[k] = __float2bfloat16(tab.e[j].s[k]);
        return;
      }
    }
    return;
  }
  int i2 = i - CVT_T13;
  if (i2 < 1024) {
    if (i2 < 746) {
      float v;
      if (i2 < 256) v = bv[i2];
      else if (i2 < 576) v = bo[i2 - 256];
      else if (i2 < 736) v = ba[i2 - 576];
      else v = br[i2 - 736];
      catbias[i2] = v;
    }
    if (i2 < 512) stats[i2] = 0.f;
    return;
  }
  i2 -= 1024;
  if (i2 < 25088) {   // 98 rows x 256 ch: conv4 bias init
    int blk = i2 >> 8, c = i2 & 255;
    int n = blk / 49, p = blk - n * 49;
    src[((size_t)(n * LTOT + 13294 + p)) * 256 + c] = bc4[c];
    return;
  }
  i2 -= 25088;
  if (i2 < 262144) {   // 256 nc x 1024 c, 9 rs each (36B contiguous read/thread)
    int nc = i2 >> 10, c = i2 & 1023;
    const float* s = Wc4f + (size_t)nc * 9216 + (size_t)c * 9;
    __hip_bfloat16* d = wt4 + (size_t)nc * 9216 + c;
#pragma unroll
    for (int rs = 0; rs < 9; rs++) d[rs * 1024] = __float2bfloat16(s[rs]);
  }
}

// fused f32 NCHW -> bf16 channel-last for x0/x2/x3 + x1->srcb lvl1 (table-driven)
__global__ __launch_bounds__(256) void transpose_all_k(
    const float* __restrict__ x0, const float* __restrict__ x2,
    const float* __restrict__ x3, const float* __restrict__ x1,
    __hip_bfloat16* __restrict__ xt0, __hip_bfloat16* __restrict__ xt2,
    __hip_bfloat16* __restrict__ xt3, __hip_bfloat16* __restrict__ srcb)
{
  __shared__ float tile[32][33];
  int b = blockIdx.x;
  const float* x; __hip_bfloat16* xt; int C, HW, gx, gy, n, lvl1 = 0;
  if (b < 2504)      { x = x0; xt = xt0; C = 128;  HW = 10000; gx = b % 313; int r = b / 313; gy = r & 3; n = r >> 2; }
  else if (b < 3144) { int bb = b - 2504; x = x2; xt = xt2; C = 512;  HW = 625; gx = bb % 20; int r = bb / 20; gy = r & 15; n = r >> 4; }
  else if (b < 3528) { int bb = b - 3144; x = x3; xt = xt3; C = 1024; HW = 169; gx = bb % 6;  int r = bb / 6;  gy = r & 31; n = r >> 5; }
  else               { int bb = b - 3528; x = x1; xt = srcb; C = 256; HW = 2500; gx = bb % 79; int r = bb / 79; gy = r & 7; n = r >> 3; lvl1 = 1; }
  int p0 = gx * 32, c0 = gy * 32;
  const float* xb = x + (size_t)n * C * HW;
  __hip_bfloat16* xtb = lvl1 ? (srcb + ((size_t)(n * LTOT + 10000)) * 256)
                             : (xt + (size_t)n * HW * C);
  int tx = threadIdx.x & 31, ty = threadIdx.x >> 5;
  for (int i = ty; i < 32; i += 8) {
    int c = c0 + i, p = p0 + tx;
    tile[i][tx] = (p < HW) ? xb[(size_t)c * HW + p] : 0.f;
  }
  __syncthreads();
  for (int i = ty; i < 32; i += 8) {
    int p = p0 + i, c = c0 + tx;
    if (p < HW) xtb[(size_t)p * C + c] = __float2bfloat16(tile[tx][i]);
  }
}

// GroupNorm raw sums for conv4 level only (li=3; levels 0-2 fused in mgemm3)
__global__ __launch_bounds__(256) void gn_stats4_k(const float* __restrict__ src,
                                                   float* __restrict__ stats)
{
  int n = blockIdx.x, t = threadIdx.x;
  const float* base = src + ((size_t)(n * LTOT + 13294)) * 256 + t;
  float s = 0.f, s2 = 0.f;
  for (int r = 0; r < 49; r++) {
    float v = base[(size_t)r * 256];
    s += v; s2 += v * v;
  }
  s  += __shfl_down(s, 4, 64);  s2 += __shfl_down(s2, 4, 64);
  s  += __shfl_down(s, 2, 64);  s2 += __shfl_down(s2, 2, 64);
  s  += __shfl_down(s, 1, 64);  s2 += __shfl_down(s2, 1, 64);
  if ((t & 7) == 0) {
    int g = t >> 3;
    int si = (3 * 2 + n) * 32 + g;
    atomicAdd(&stats[si * 2],     s);
    atomicAdd(&stats[si * 2 + 1], s2);
  }
}

// merged GN apply + finalize -> bf16 only; grid 21686 blocks
__global__ __launch_bounds__(256) void gn_apply_k(const float* __restrict__ src,
    __hip_bfloat16* __restrict__ srcb,
    const float* __restrict__ stats, const float* __restrict__ g,
    const float* __restrict__ b)
{
  int x = blockIdx.x;
  int n = x / 10843, cidx = x - n * 10843;
  int li, off, hw, p;
  if (cidx < 10000)      { li = 0; off = 0;     hw = 10000; p = cidx; }
  else if (cidx < 10625) { li = 1; off = 12500; hw = 625;   p = cidx - 10000; }
  else if (cidx < 10794) { li = 2; off = 13125; hw = 169;   p = cidx - 10625; }
  else                   { li = 3; off = 13294; hw = 49;    p = cidx - 10794; }
  int t = threadIdx.x;
  int si = (li * 2 + n) * 32 + (t >> 3);
  float cnt = (float)(hw * 8);
  float mean = stats[si * 2] / cnt;
  float var = stats[si * 2 + 1] / cnt - mean * mean;
  float rstd = rsqrtf(var + 1e-5f);
  size_t a = ((size_t)(n * LTOT + off + p)) * 256 + t;
  float v = (src[a] - mean) * rstd * g[t] + b[t];
  srcb[a] = __float2bfloat16(v);
}

// ---------------------------------------------------------------------------
// deformable sampling v6b (PROVEN OPTIMUM — rounds 6/7/13 wider variants all
// lost to occupancy/conflict displacement): block = 2 queries; fused softmax;
// f16 value/off/aw; gather 2 ch/thread via dword load + packed f16 fma.
// LDS ~12 KB, VGPR 32, conflicts 0.
// [R1: 1-query-per-wave + dwordx2 halved MLP -> latency-bound, 83us. FAIL]
// [R2: saddr/readfirstlane gathers cut VALU 12% but exposed vmcnt stalls
//  (VALUBusy 83->65, dur 71.3->79.7us). The addr adds are free under load
//  latency. Do NOT restructure this gather; 71.3us is the local optimum.]
// ---------------------------------------------------------------------------
__global__ __launch_bounds__(256) void msdeform_k(const _Float16* __restrict__ value,
    const _Float16* __restrict__ offb, const _Float16* __restrict__ awb,
    const float* __restrict__ refb, __hip_bfloat16* __restrict__ out)
{
  __shared__ float s_awraw[320];
  __shared__ float s_ref[20];
  __shared__ float s_stat[32];
  __shared__ int4 s_cA[320];   // [ql*160 + h*20+pt] -> off00,w00p,off10,w10p
  __shared__ int4 s_cB[320];   //                     -> off01,w01p,off11,w11p
  const int t = threadIdx.x;
  const int q0 = blockIdx.x * 2;

  for (int i = t; i < 320; i += 256) {
    int ql = (i >= 160) ? 1 : 0;
    s_awraw[i] = (float)awb[(size_t)(q0 + ql) * 160 + (i - ql * 160)];
  }
  if (t < 20) {
    int ql = (t >= 10) ? 1 : 0;
    s_ref[t] = refb[(size_t)(q0 + ql) * 10 + (t - ql * 10)];
  }
  __syncthreads();

  if (t < 16) {
    const float* p = s_awraw + t * 20;
    float m = p[0];
#pragma unroll
    for (int j = 1; j < 20; j++) m = fmaxf(m, p[j]);
    float s = 0.f;
#pragma unroll
    for (int j = 0; j < 20; j++) s += expf(p[j] - m);
    s_stat[t * 2] = m;
    s_stat[t * 2 + 1] = 1.f / s;
  }
  __syncthreads();

  {
    const int Wl[5]   = {100, 50, 25, 13, 7};
    const int lvlo[5] = {0, 10000, 12500, 13125, 13294};
    for (int i = t; i < 320; i += 256) {
      int ql = (i >= 160) ? 1 : 0;
      int j = i - ql * 160;
      int h = j / 20, pt = j - h * 20;
      int l = pt >> 2;
      int q = q0 + ql;
      int W = Wl[l], lo = lvlo[l];
      float fW = (float)W;
      f16x2 o2h = *(const f16x2*)(offb + (size_t)q * 320 + j * 2);
      float ox = (float)o2h[0], oy = (float)o2h[1];
      int hs = (ql * 8 + h) * 2;
      float wgt = expf(s_awraw[i] - s_stat[hs]) * s_stat[hs + 1];
      float rx = s_ref[ql * 10 + l * 2], ry = s_ref[ql * 10 + l * 2 + 1];
      float x = (rx + ox / fW) * fW - 0.5f;
      float y = (ry + oy / fW) * fW - 0.5f;
      float x0f = floorf(x), y0f = floorf(y);
      float wx = x - x0f, wy = y - y0f;
      int x0 = (int)x0f, y0 = (int)y0f;
      int hb = h * 64;
      auto mk = [&](int ix, int iy, float w) {
        bool v = (ix >= 0) & (ix < W) & (iy >= 0) & (iy < W);
        int cx = min(max(ix, 0), W - 1), cy = min(max(iy, 0), W - 1);
        int off = (lo + cy * W + cx) * 512 + hb;
        float fw = v ? w * wgt : 0.f;
        unsigned hbits = (unsigned)__builtin_bit_cast(unsigned short, (_Float16)fw);
        return make_int2(off, (int)(hbits | (hbits << 16)));
      };
      int2 c00 = mk(x0,     y0,     (1.f - wx) * (1.f - wy));
      int2 c10 = mk(x0 + 1, y0,     wx * (1.f - wy));
      int2 c01 = mk(x0,     y0 + 1, (1.f - wx) * wy);
      int2 c11 = mk(x0 + 1, y0 + 1, wx * wy);
      s_cA[i] = make_int4(c00.x, c00.y, c10.x, c10.y);
      s_cB[i] = make_int4(c01.x, c01.y, c11.x, c11.y);
    }
  }
  __syncthreads();

  const int ql = t >> 7, h = (t >> 4) & 7, c2 = t & 15;
  const int q = q0 + ql;
  const int n = q / LTOT;
  const char* vb = (const char*)value + (size_t)n * LTOT * 512 + c2 * 4;
  f16x2 accA = {0, 0}, accB = {0, 0};
  const int bi = ql * 160 + h * 20;
#pragma unroll 5
  for (int p = 0; p < 20; p++) {
    int4 A = s_cA[bi + p];
    int4 B = s_cB[bi + p];
    {
      f16x2 v2 = __builtin_bit_cast(f16x2, *(const unsigned*)(vb + A.x));
      f16x2 w2 = __builtin_bit_cast(f16x2, (unsigned)A.y);
      accA = w2 * v2 + accA;
    }
    {
      f16x2 v2 = __builtin_bit_cast(f16x2, *(const unsigned*)(vb + A.z));
      f16x2 w2 = __builtin_bit_cast(f16x2, (unsigned)A.w);
      accB = w2 * v2 + accB;
    }
    {
      f16x2 v2 = __builtin_bit_cast(f16x2, *(const unsigned*)(vb + B.x));
      f16x2 w2 = __builtin_bit_cast(f16x2, (unsigned)B.y);
      accA = w2 * v2 + accA;
    }
    {
      f16x2 v2 = __builtin_bit_cast(f16x2, *(const unsigned*)(vb + B.z));
      f16x2 w2 = __builtin_bit_cast(f16x2, (unsigned)B.w);
      accB = w2 * v2 + accB;
    }
  }
  float a0 = (float)accA[0] + (float)accB[0];
  float a1 = (float)accA[1] + (float)accB[1];
  unsigned o0 = (unsigned)f2bu(a0);
  unsigned o1 = (unsigned)f2bu(a1);
  *(unsigned*)((char*)out + ((size_t)q * 256 + h * 32 + c2 * 2) * 2) = (o1 << 16) | o0;
}

extern "C" void kernel_launch(void* const* d_in, const int* in_sizes, int n_in,
                              void* d_out, int out_size, void* d_ws, size_t ws_size,
                              hipStream_t stream)
{
  const float* x0    = (const float*)d_in[0];
  const float* x1    = (const float*)d_in[1];
  const float* x2    = (const float*)d_in[2];
  const float* x3    = (const float*)d_in[3];
  const float* W_ref = (const float*)d_in[4];
  const float* b_ref = (const float*)d_in[5];
  const float* W_off = (const float*)d_in[6];
  const float* b_off = (const float*)d_in[7];
  const float* W_aw  = (const float*)d_in[8];
  const float* b_aw  = (const float*)d_in[9];
  const float* W_val = (const float*)d_in[10];
  const float* b_val = (const float*)d_in[11];
  const float* W_outp= (const float*)d_in[12];
  const float* b_outp= (const float*)d_in[13];
  const float* gn_g  = (const float*)d_in[14];
  const float* gn_b  = (const float*)d_in[15];
  const float* Wc1   = (const float*)d_in[16];
  const float* bc1   = (const float*)d_in[17];
  const float* Wc2   = (const float*)d_in[18];
  const float* bc2   = (const float*)d_in[19];
  const float* Wc3   = (const float*)d_in[20];
  const float* bc3   = (const float*)d_in[21];
  const float* Wc4   = (const float*)d_in[22];
  const float* bc4   = (const float*)d_in[23];
  const float* Wc11  = (const float*)d_in[24];
  const float* bc11  = (const float*)d_in[25];
  const float* Wc22  = (const float*)d_in[26];
  const float* bc22  = (const float*)d_in[27];
  const float* Wc33  = (const float*)d_in[28];
  const float* bc33  = (const float*)d_in[29];
  const float* ln1_g = (const float*)d_in[30];
  const float* ln1_b = (const float*)d_in[31];
  const float* W1    = (const float*)d_in[32];
  const float* b1f   = (const float*)d_in[33];
  const float* W2    = (const float*)d_in[34];
  const float* b2f_  = (const float*)d_in[35];
  const float* ln2_g = (const float*)d_in[36];
  const float* ln2_b = (const float*)d_in[37];

  // ---- workspace (byte offsets) ----
  char* wsb = (char*)d_ws;
  float* src             = (float*)(wsb + 0);
  _Float16* valb         = (_Float16*)(wsb + WS_VALB);
  __hip_bfloat16* h2b    = (__hip_bfloat16*)(wsb + 54652928);
  __hip_bfloat16* srcb   = (__hip_bfloat16*)(wsb + 81979392);
  __hip_bfloat16* h1b    = (__hip_bfloat16*)(wsb + 95642624);
  __hip_bfloat16* sampb  = (__hip_bfloat16*)(wsb + 109305856);
  _Float16* offbh        = (_Float16*)(wsb + WS_R);
  _Float16* awbh         = (_Float16*)(wsb + WS_AW);
  float* refb            = (float*)(wsb + WS_REF);
  __hip_bfloat16* xt0    = (__hip_bfloat16*)(wsb + WS_R);
  __hip_bfloat16* xt2    = (__hip_bfloat16*)(wsb + WS_R + 5120000);
  __hip_bfloat16* xt3    = (__hip_bfloat16*)(wsb + WS_R + 6400000);
  // conv4 pre-transposed W (4.7 MB): hole after xt3, before offb/midb written
  __hip_bfloat16* wWc4t  = (__hip_bfloat16*)(wsb + WS_R + 8388608);
  __hip_bfloat16* warena = (__hip_bfloat16*)(wsb + 177622016);
  float* stats           = (float*)(wsb + 180887552);
  float* catbias         = (float*)(wsb + 180889600);
  const size_t needed = 180892672;
  if (ws_size < needed) return;

  __hip_bfloat16* wWproj = warena + 0;
  __hip_bfloat16* wW_val = warena + 0;
  __hip_bfloat16* wW_off = warena + 65536;
  __hip_bfloat16* wW_aw  = warena + 147456;
  __hip_bfloat16* wW_ref = warena + 188416;
  __hip_bfloat16* wW_out = warena + 190976;
  __hip_bfloat16* wW1    = warena + 256512;
  __hip_bfloat16* wW2    = warena + 518656;
  __hip_bfloat16* wWc1   = warena + 780800;
  __hip_bfloat16* wWc2   = warena + 813568;
  __hip_bfloat16* wWc3   = warena + 944640;
  __hip_bfloat16* wWc11  = warena + 1206784;
  __hip_bfloat16* wWc22  = warena + 1239552;
  __hip_bfloat16* wWc33  = warena + 1370624;

  dim3 B(256);

  CvtTab tab = {{
    {W_val, wW_val, 65536, 0},       {W_off, wW_off, 81920, 65536},
    {W_aw,  wW_aw,  40960, 147456},  {W_ref, wW_ref, 2560,  188416},
    {W_outp,wW_out, 65536, 190976},  {W1,    wW1,  262144,  256512},
    {W2,    wW2,  262144,  518656},  {Wc1,   wWc1,  32768,  780800},
    {Wc2,   wWc2, 131072,  813568},  {Wc3,   wWc3, 262144,  944640},
    {Wc11,  wWc11, 32768, 1206784},  {Wc22,  wWc22,131072, 1239552},
    {Wc33,  wWc33,262144, 1370624}
  }};
  cvt_weights_k<<<7504,B,0,stream>>>(tab, b_val, b_off, b_aw, b_ref,
                                     catbias, stats, src, bc4, Wc4, wWc4t);

  // ---- phase 1: fused transposes (incl. x1->srcb lvl1), convs(+stats)+conv4, GN ----
  transpose_all_k<<<4792,B,0,stream>>>(x0, x2, x3, x1, xt0, xt2, xt3, srcb);

  GJobs injobs = {{
    { xt0, wWc1, bc1, src, 20000, 256, 128,  20000, 0, 0, 10000, LTOT, 0,     0,   313 },
    { xt2, wWc2, bc2, src, 1250,  256, 512,  1250,  0, 0, 625,   LTOT, 12500, 626, 20  },
    { xt3, wWc3, bc3, src, 338,   256, 1024, 338,   0, 0, 169,   LTOT, 13125, 666, 6   }
  }};
  mgemm3_k<0,false,true><<<806,B,0,stream>>>(injobs, 678, nullptr, nullptr,
                                             xt3, wWc4t, src, stats);
  gn_stats4_k<<<2,B,0,stream>>>(src, stats);
  gn_apply_k<<<21686,B,0,stream>>>(src, srcb, stats, gn_g, gn_b);

  // ---- fused projections + sampling ----
  mgemm_k<128,0,7,0><<<dim3(209,6),B,0,stream>>>(srcb, wWproj, catbias, d_ws, nullptr, nullptr, nullptr, NLQ,746,256,256, NLQ,0,0, NLQ,0,0);
  msdeform_k<<<13343,B,0,stream>>>(valb, offbh, awbh, refb, sampb);

  // ---- out-proj + resid(srcb) + LN1 fused (EPI9) -> h1b ----
  mgemm_k<64,0,9,0><<<dim3(417,1),B,0,stream>>>(sampb, wW_out, b_outp, h1b, srcb, ln1_g, ln1_b, NLQ,256,256,256, NLQ,0,0, NLQ,0,0);

  // ---- fused FFN v2 (32-row blocks) -> h2b, no midb round-trip ----
  ffn_k<<<834,B,0,stream>>>(h1b, wW1, b1f, wW2, b2f_, ln2_g, ln2_b, h2b);

  // ---- output convs + lvl1 copy-out, single launch ----
  float* out = (float*)d_out;
  GJobs outjobs = {{
    { h2b, wWc11, bc11, out,           20000, 128,  256, 10000, LTOT, 0,     10000, 0, 0, 0,   313 },
    { h2b, wWc22, bc22, out + 3840000, 1250,  512,  256, 625,   LTOT, 12500, 625,   0, 0, 313, 20  },
    { h2b, wWc33, bc33, out + 4480000, 338,   1024, 256, 169,   LTOT, 13125, 169,   0, 0, 393, 6   }
  }};
  mgemm3_k<4,true,false><<<1705,B,0,stream>>>(outjobs, 441, h2b, out + 2560000,
                                              nullptr, nullptr, nullptr, nullptr);
}

// Round 10
// 459.803 us; speedup vs baseline: 1.1499x; 1.1499x over previous
//
#include <hip/hip_runtime.h>
#include <hip/hip_bf16.h>
#include <hip/hip_fp16.h>

// I/O f32. Internal: bf16 MFMA GEMMs, f16 value/off/aw + packed-f16 sampling,
// bf16 residual path (threshold 9.9e-2 budgets low-precision internals).
// Levels (100,100),(50,50),(25,25),(13,13),(7,7); offsets 0,10000,12500,13125,13294
#define LTOT 13343
#define NLQ  26686
// fixed workspace byte offsets (used inside EPI7 epilogue)
#define WS_VALB 27326464
#define WS_R    122969088
#define WS_AW   (WS_R + 17079040)
#define WS_REF  (WS_R + 25618560)

typedef __attribute__((ext_vector_type(8))) short bf16x8;
typedef __attribute__((ext_vector_type(4))) float f32x4;
typedef _Float16 f16x2 __attribute__((ext_vector_type(2)));

__device__ __forceinline__ short f2bs(float x) {
  __hip_bfloat16 h = __float2bfloat16(x);
  return __builtin_bit_cast(short, h);
}
__device__ __forceinline__ float b2f(__hip_bfloat16 x) { return __bfloat162float(x); }
__device__ __forceinline__ unsigned short f2bu(float x) {
  return __builtin_bit_cast(unsigned short, __float2bfloat16(x));
}

// async global->LDS 16B per lane; LDS dst must be wave-uniform base (+lane*16)
__device__ __forceinline__ void gld16(const void* g, void* l) {
  __builtin_amdgcn_global_load_lds(
      (const __attribute__((address_space(1))) void*)g,
      (__attribute__((address_space(3))) void*)l, 16, 0, 0);
}

// ---------------------------------------------------------------------------
// MFMA GEMM: out = epi(A(bf16) @ W^T + bias)
// MT=128: 128x128 tile, 4 waves 64x64; MT=64: 64x128 tile, 4 waves 64x32.
// EPI9: 64x256 tile (4 waves 64x64 cols, JF=4) so a block owns full 256-col
//       rows -> fused bias + residual + bf16-round + row-LayerNorm epilogue.
// FAST path (AMODE0/WMODE0): BK=64 double-panel staging, one barrier pair per
// 64-K. LDS: MT128 32KB, MT64 24KB, EPI9 40KB.
// EPI: 0 bias->f32 rowmap | 1 bias+sigmoid->f32 | 2 bias+relu->bf16 rowmap
//      3 atomicAdd f32 | 4 bias->f32 NCHW | 6 bias->bf16 rowmap
//      7 fused projection (val f16|off f16|aw f16|ref sigmoid f32)
//      8 bias + residual(bf16) -> bf16 rowmap
//      9 bias + residual(bf16) -> bf16-round -> LayerNorm(row,256) -> bf16
// ---------------------------------------------------------------------------
template<int MT, int AMODE, int EPI, int WMODE>
__global__ __launch_bounds__(256) void mgemm_k(
    const __hip_bfloat16* __restrict__ A, const void* __restrict__ Wv,
    const float* __restrict__ bias, void* __restrict__ outv,
    const __hip_bfloat16* __restrict__ resid,
    const float* __restrict__ lng, const float* __restrict__ lnb,
    int M, int Nc, int K, int k_len,
    int A_HW, int A_L, int A_off,
    int O_HW, int O_L, int O_off)
{
  constexpr int NT = (EPI == 9) ? 256 : 128;
  constexpr int JF = (MT == 128 || EPI == 9) ? 4 : 2;
  constexpr bool FAST = (AMODE == 0 && WMODE == 0);
  constexpr int AK = FAST ? 64 : 32;
  constexpr int PA = MT * 32;
  constexpr int PB = NT * 32;
  __shared__ __hip_bfloat16 ldsA[MT * AK];
  __shared__ __hip_bfloat16 ldsB[NT * AK];
  const int t = threadIdx.x;
  const int bm = blockIdx.x * MT, bn = blockIdx.y * NT;
  const int k0 = blockIdx.z * k_len;

  const int sl = t & 63;
  const int mloc = sl & 15;
  const int kbase = (sl >> 4) * 8;
  const int s0 = t >> 6;

  const int r0 = bm + s0 * 16 + mloc, r1 = r0 + 64;
  const int nc0 = bn + s0 * 16 + mloc, nc1 = nc0 + 64;
  const int nc2 = nc0 + 128, nc3 = nc0 + 192;

  const __hip_bfloat16 *ap0 = A, *ap1 = A;
  bool av0 = false, av1 = false;
  int g0n=0, g0h=0, g0w=0, g1n=0, g1h=0, g1w=0;
  if (AMODE == 0) {
    if (r0 < M) { int nn = r0 / A_HW, p = r0 - nn * A_HW;
      ap0 = A + (size_t)(nn * A_L + A_off + p) * K + kbase; av0 = true; }
    if (MT == 128 && r1 < M) { int nn = r1 / A_HW, p = r1 - nn * A_HW;
      ap1 = A + (size_t)(nn * A_L + A_off + p) * K + kbase; av1 = true; }
  } else {
    if (r0 < M) { g0n = r0 / 49; int p = r0 - g0n * 49; g0h = p / 7; g0w = p - g0h * 7; av0 = true; }
    if (r1 < M) { g1n = r1 / 49; int p = r1 - g1n * 49; g1h = p / 7; g1w = p - g1h * 7; av1 = true; }
  }
  const bool wv0 = nc0 < Nc, wv1 = nc1 < Nc;
  const bool wv2 = (EPI == 9) && (nc2 < Nc), wv3 = (EPI == 9) && (nc3 < Nc);
  const __hip_bfloat16 *wb0 = (const __hip_bfloat16*)Wv, *wb1 = wb0, *wb2 = wb0, *wb3 = wb0;
  const float *wf0 = (const float*)Wv, *wf1 = wf0;
  if (WMODE == 0) {
    if (wv0) wb0 = (const __hip_bfloat16*)Wv + (size_t)nc0 * K + kbase;
    if (wv1) wb1 = (const __hip_bfloat16*)Wv + (size_t)nc1 * K + kbase;
    if (wv2) wb2 = (const __hip_bfloat16*)Wv + (size_t)nc2 * K + kbase;
    if (wv3) wb3 = (const __hip_bfloat16*)Wv + (size_t)nc3 * K + kbase;
  } else {
    if (wv0) wf0 = (const float*)Wv + (size_t)nc0 * 9216;
    if (wv1) wf1 = (const float*)Wv + (size_t)nc1 * 9216;
  }

  __hip_bfloat16* lbA0 = ldsA + s0 * 512;
  __hip_bfloat16* lbA1 = lbA0 + 2048;
  __hip_bfloat16* lbB0 = ldsB + s0 * 512;
  __hip_bfloat16* lbB1 = lbB0 + 2048;
  __hip_bfloat16* lbB2 = lbB0 + 4096;
  __hip_bfloat16* lbB3 = lbB0 + 6144;
  __hip_bfloat16* lwA0 = ldsA + s0 * 512 + sl * 8;
  __hip_bfloat16* lwA1 = lwA0 + 2048;
  __hip_bfloat16* lwB0 = ldsB + s0 * 512 + sl * 8;
  __hip_bfloat16* lwB1 = lwB0 + 2048;

  const int lane = t & 63, wv_ = t >> 6;
  const __hip_bfloat16 *rA, *rB;
  int wmR, colbase;
  if (MT == 128) {
    int wm = wv_ >> 1, wn = wv_ & 1;
    rA = ldsA + wm * 2048 + lane * 8;
    rB = ldsB + wn * 2048 + lane * 8;
    wmR = wm * 64;
    colbase = bn + wn * 64;
  } else if (EPI == 9) {
    rA = ldsA + lane * 8;
    rB = ldsB + wv_ * 2048 + lane * 8;
    wmR = 0;
    colbase = bn + wv_ * 64;
  } else {
    rA = ldsA + lane * 8;
    rB = ldsB + wv_ * 1024 + lane * 8;
    wmR = 0;
    colbase = bn + wv_ * 32;
  }

  f32x4 acc[4][JF] = {};

  if (FAST) {
    for (int kt = k0; kt < k0 + k_len; kt += 64) {
      if (av0) { gld16(ap0 + kt, lbA0); gld16(ap0 + kt + 32, lbA0 + PA); }
      if (MT == 128) {
        if (av1) { gld16(ap1 + kt, lbA1); gld16(ap1 + kt + 32, lbA1 + PA); }
      }
      if (wv0) { gld16(wb0 + kt, lbB0); gld16(wb0 + kt + 32, lbB0 + PB); }
      if (wv1) { gld16(wb1 + kt, lbB1); gld16(wb1 + kt + 32, lbB1 + PB); }
      if (EPI == 9) {
        if (wv2) { gld16(wb2 + kt, lbB2); gld16(wb2 + kt + 32, lbB2 + PB); }
        if (wv3) { gld16(wb3 + kt, lbB3); gld16(wb3 + kt + 32, lbB3 + PB); }
      }
      __syncthreads();
#pragma unroll
      for (int h = 0; h < 2; h++) {
        bf16x8 af[4], bfr[JF];
#pragma unroll
        for (int i = 0; i < 4; i++) af[i] = *(const bf16x8*)(rA + h * PA + i * 512);
#pragma unroll
        for (int j = 0; j < JF; j++) bfr[j] = *(const bf16x8*)(rB + h * PB + j * 512);
#pragma unroll
        for (int i = 0; i < 4; i++)
#pragma unroll
          for (int j = 0; j < JF; j++)
            acc[i][j] = __builtin_amdgcn_mfma_f32_16x16x32_bf16(af[i], bfr[j], acc[i][j], 0, 0, 0);
      }
      __syncthreads();
    }
  } else {
    for (int kt = k0; kt < k0 + k_len; kt += 32) {
      {
        bf16x8 va0 = {}, va1 = {};
        int kp = kt + kbase;
        int rs = kp >> 10, c = kp & 1023;
        int rr = rs / 3, ss = rs - rr * 3;
        if (av0) { int ih = g0h*2-1+rr, iw = g0w*2-1+ss;
          if ((unsigned)ih < 13u && (unsigned)iw < 13u)
            va0 = *(const bf16x8*)(A + ((size_t)(g0n*169 + ih*13 + iw))*1024 + c); }
        if (av1) { int ih = g1h*2-1+rr, iw = g1w*2-1+ss;
          if ((unsigned)ih < 13u && (unsigned)iw < 13u)
            va1 = *(const bf16x8*)(A + ((size_t)(g1n*169 + ih*13 + iw))*1024 + c); }
        *(bf16x8*)lwA0 = va0;  *(bf16x8*)lwA1 = va1;
      }
      {
        bf16x8 vb0 = {}, vb1 = {};
        int kp = kt + kbase;
        int rs = kp >> 10, c = kp & 1023;
        if (wv0) { const float* p = wf0 + (size_t)c * 9 + rs;
#pragma unroll
          for (int j = 0; j < 8; j++) vb0[j] = f2bs(p[j * 9]); }
        if (wv1) { const float* p = wf1 + (size_t)c * 9 + rs;
#pragma unroll
          for (int j = 0; j < 8; j++) vb1[j] = f2bs(p[j * 9]); }
        *(bf16x8*)lwB0 = vb0;  *(bf16x8*)lwB1 = vb1;
      }
      __syncthreads();
      bf16x8 af[4], bfr[JF];
#pragma unroll
      for (int i = 0; i < 4; i++) af[i] = *(const bf16x8*)(rA + i * 512);
#pragma unroll
      for (int j = 0; j < JF; j++) bfr[j] = *(const bf16x8*)(rB + j * 512);
#pragma unroll
      for (int i = 0; i < 4; i++)
#pragma unroll
        for (int j = 0; j < JF; j++)
          acc[i][j] = __builtin_amdgcn_mfma_f32_16x16x32_bf16(af[i], bfr[j], acc[i][j], 0, 0, 0);
      __syncthreads();
    }
  }

  // epilogue: C/D map col=lane&15, row=(lane>>4)*4+reg
  const int quad = lane >> 4, nl = lane & 15;

  if constexpr (EPI == 9) {
    // fused bias + residual + bf16-round + row LayerNorm over Nc=256.
    // reduction scratch in ldsB (safe: K-loop ended on __syncthreads).
    float* red  = (float*)ldsB;          // [64 rows] stride 9: {sum, sumsq} x 4 waves
    float* redm = (float*)ldsB + 600;    // [64 rows] x {mean, rstd}
    float bv9[4], gj[4], bj[4]; int cj9[4];
#pragma unroll
    for (int j = 0; j < 4; j++) {
      cj9[j] = colbase + j * 16 + nl;
      bv9[j] = bias[cj9[j]];
      gj[j]  = lng[cj9[j]];
      bj[j]  = lnb[cj9[j]];
    }
#pragma unroll
    for (int i = 0; i < 4; i++) {
#pragma unroll
      for (int r = 0; r < 4; r++) {
        int row64 = i * 16 + quad * 4 + r;
        int m = bm + row64;
        if (m < M) {
          int n = m / O_HW, p = m - n * O_HW;
          size_t orow = (size_t)(n * O_L + O_off + p);
#pragma unroll
          for (int j = 0; j < 4; j++) {
            float v = acc[i][j][r] + bv9[j] + b2f(resid[orow * Nc + cj9[j]]);
            acc[i][j][r] = b2f(__float2bfloat16(v));  // round first, stats on rounded
          }
        } else {
#pragma unroll
          for (int j = 0; j < 4; j++) acc[i][j][r] = 0.f;
        }
        float s  = acc[i][0][r] + acc[i][1][r] + acc[i][2][r] + acc[i][3][r];
        float s2 = acc[i][0][r]*acc[i][0][r] + acc[i][1][r]*acc[i][1][r]
                 + acc[i][2][r]*acc[i][2][r] + acc[i][3][r]*acc[i][3][r];
        // reduce across the 16-lane col group (quad fixed within group)
        s  += __shfl_xor(s, 1, 64);  s2 += __shfl_xor(s2, 1, 64);
        s  += __shfl_xor(s, 2, 64);  s2 += __shfl_xor(s2, 2, 64);
        s  += __shfl_xor(s, 4, 64);  s2 += __shfl_xor(s2, 4, 64);
        s  += __shfl_xor(s, 8, 64);  s2 += __shfl_xor(s2, 8, 64);
        if (nl == 0) { red[row64 * 9 + wv_ * 2] = s; red[row64 * 9 + wv_ * 2 + 1] = s2; }
      }
    }
    __syncthreads();
    if (t < 64) {
      float S = 0.f, S2 = 0.f;
#pragma unroll
      for (int w = 0; w < 4; w++) { S += red[t * 9 + w * 2]; S2 += red[t * 9 + w * 2 + 1]; }
      float mean = S * (1.f / 256.f);
      float var  = S2 * (1.f / 256.f) - mean * mean;
      redm[t * 2]     = mean;
      redm[t * 2 + 1] = rsqrtf(var + 1e-5f);
    }
    __syncthreads();
#pragma unroll
    for (int i = 0; i < 4; i++) {
#pragma unroll
      for (int r = 0; r < 4; r++) {
        int row64 = i * 16 + quad * 4 + r;
        int m = bm + row64;
        if (m >= M) continue;
        float mean = redm[row64 * 2], rstd = redm[row64 * 2 + 1];
        int n = m / O_HW, p = m - n * O_HW;
        size_t orow = (size_t)(n * O_L + O_off + p);
#pragma unroll
        for (int j = 0; j < 4; j++) {
          float o = (acc[i][j][r] - mean) * rstd * gj[j] + bj[j];
          ((__hip_bfloat16*)outv)[orow * Nc + cj9[j]] = __float2bfloat16(o);
        }
      }
    }
    return;
  }

  float bv[JF]; int cj[JF]; bool cv[JF];
#pragma unroll
  for (int j = 0; j < JF; j++) {
    cj[j] = colbase + j * 16 + nl;
    cv[j] = cj[j] < Nc;
    bv[j] = (EPI != 3 && cv[j]) ? bias[cj[j]] : 0.f;
  }
#pragma unroll
  for (int i = 0; i < 4; i++) {
#pragma unroll
    for (int r = 0; r < 4; r++) {
      int m = bm + wmR + i * 16 + quad * 4 + r;
      if (m >= M) continue;
      int n = m / O_HW, p = m - n * O_HW;
      size_t orow = (size_t)(n * O_L + O_off + p);
#pragma unroll
      for (int j = 0; j < JF; j++) {
        if (!cv[j]) continue;
        float v = acc[i][j][r] + bv[j];
        if (EPI == 1) v = 1.f / (1.f + expf(-v));
        if (EPI == 2) v = fmaxf(v, 0.f);
        if (EPI == 0 || EPI == 1) ((float*)outv)[orow * Nc + cj[j]] = v;
        else if (EPI == 2 || EPI == 6) ((__hip_bfloat16*)outv)[orow * Nc + cj[j]] = __float2bfloat16(v);
        else if (EPI == 3) atomicAdd((float*)outv + orow * Nc + cj[j], acc[i][j][r]);
        else if (EPI == 8) {
          float rv = b2f(resid[orow * Nc + cj[j]]);
          ((__hip_bfloat16*)outv)[orow * Nc + cj[j]] = __float2bfloat16(v + rv);
        }
        else if (EPI == 7) {
          char* base = (char*)outv;
          int q = m, c = cj[j];
          if (c < 256)
            ((_Float16*)(base + WS_VALB))[(size_t)q * 256 + c] = (_Float16)v;
          else if (c < 576)
            ((_Float16*)(base + WS_R))[(size_t)q * 320 + (c - 256)] = (_Float16)v;
          else if (c < 736)
            ((_Float16*)(base + WS_AW))[(size_t)q * 160 + (c - 576)] = (_Float16)v;
          else {
            float sv = 1.f / (1.f + expf(-v));
            ((float*)(base + WS_REF))[(size_t)q * 10 + (c - 736)] = sv;
          }
        }
        else ((float*)outv)[((size_t)n * Nc + cj[j]) * O_HW + p] = v;
      }
    }
  }
}

// ---------------------------------------------------------------------------
// fused FFN (v1, PROVEN BEST): out = LN2(h1 + relu(h1@W1^T+b1)@W2^T + b2),
// bit-identical to split FFN1(EPI2)+FFN2(EPI9). 417 blocks x 256 thr,
// 64 rows/block. LDS 64KB: A(32K resident) + mid(16K frag layout) +
// W staging(16K). Saves midb 109MB round-trip + FFN1's 8x A re-read.
// [R7: 81us, occ 17%, MfmaUtil 13% -- barrier-bound but total 461us = best.]
// [R9: 32-row v2 (40KB, 834 blocks) HALVED MFMA-per-barrier -> 163us, occ 21%,
//  MfmaUtil 6.7%. Barrier-issue-bound: smaller tiles make it WORSE. Do NOT
//  shrink this tile; deep pipelining is the only (unexplored, risky) lever.]
// ---------------------------------------------------------------------------
__global__ __launch_bounds__(256) void ffn_k(
    const __hip_bfloat16* __restrict__ h1, const __hip_bfloat16* __restrict__ W1,
    const float* __restrict__ b1, const __hip_bfloat16* __restrict__ W2,
    const float* __restrict__ b2, const float* __restrict__ lng,
    const float* __restrict__ lnb, __hip_bfloat16* __restrict__ out)
{
  __shared__ char smem[65536];
  __hip_bfloat16* ldsA = (__hip_bfloat16*)smem;             // 32KB: 64 rows x 256 K
  __hip_bfloat16* ldsM = (__hip_bfloat16*)(smem + 32768);   // 16KB: 64 x 128 mid
  __hip_bfloat16* ldsW = (__hip_bfloat16*)(smem + 49152);   // 16KB: 128 x 64 W panel
  const int t = threadIdx.x;
  const int bm = blockIdx.x * 64;
  const int sl = t & 63, mloc = sl & 15, kbase = (sl >> 4) * 8, s0 = t >> 6;
  const int lane = t & 63, wv_ = t >> 6;
  const int quad = lane >> 4, nl = lane & 15;

  // stage A = h1 rows [bm, bm+64) x K=256 resident (4 panels of 64K)
  const int r0 = bm + s0 * 16 + mloc;
  if (r0 < NLQ) {
    const __hip_bfloat16* ap = h1 + (size_t)r0 * 256 + kbase;
#pragma unroll
    for (int p = 0; p < 4; p++) {
      gld16(ap + p * 64,      ldsA + p * 4096 + s0 * 512);
      gld16(ap + p * 64 + 32, ldsA + p * 4096 + s0 * 512 + 2048);
    }
  }

  const int ca = s0 * 16 + mloc;   // staging col within a 128-col group
  const __hip_bfloat16* rA = ldsA + lane * 8;
  const __hip_bfloat16* rM = ldsM + lane * 8;
  const __hip_bfloat16* rB = ldsW + wv_ * 1024 + lane * 8;

  f32x4 acc2[4][4] = {};

  for (int c = 0; c < 8; c++) {
    // ---- GEMM1: mid[64x128] = A @ W1[c*128 .. +127]^T  (K=256) ----
    f32x4 acc1[4][2] = {};
    const __hip_bfloat16* wp0 = W1 + (size_t)(c * 128 + ca) * 256 + kbase;
    const __hip_bfloat16* wp1 = wp0 + (size_t)64 * 256;
    for (int kt = 0; kt < 256; kt += 64) {
      gld16(wp0 + kt,      ldsW + s0 * 512);
      gld16(wp0 + kt + 32, ldsW + s0 * 512 + 4096);
      gld16(wp1 + kt,      ldsW + s0 * 512 + 2048);
      gld16(wp1 + kt + 32, ldsW + s0 * 512 + 2048 + 4096);
      __syncthreads();
      const int p = kt >> 6;
#pragma unroll
      for (int h = 0; h < 2; h++) {
        bf16x8 af[4], bfr[2];
#pragma unroll
        for (int i = 0; i < 4; i++) af[i] = *(const bf16x8*)(rA + p * 4096 + h * 2048 + i * 512);
#pragma unroll
        for (int j = 0; j < 2; j++) bfr[j] = *(const bf16x8*)(rB + h * 4096 + j * 512);
#pragma unroll
        for (int i = 0; i < 4; i++)
#pragma unroll
          for (int j = 0; j < 2; j++)
            acc1[i][j] = __builtin_amdgcn_mfma_f32_16x16x32_bf16(af[i], bfr[j], acc1[i][j], 0, 0, 0);
      }
      __syncthreads();
    }
    // bias + relu + bf16-round -> ldsM in canonical A-frag layout
    // L(row,k) = (k>>6)*4096 + ((k>>5)&1)*2048 + (row>>4)*512
    //          + ((k>>3)&3)*128 + (row&15)*8 + (k&7)
#pragma unroll
    for (int j = 0; j < 2; j++) {
      int kc = wv_ * 32 + j * 16 + nl;
      float bb = b1[c * 128 + kc];
      int ka = (kc >> 6) * 4096 + ((kc >> 5) & 1) * 2048 + ((kc >> 3) & 3) * 128 + (kc & 7);
#pragma unroll
      for (int i = 0; i < 4; i++)
#pragma unroll
        for (int r = 0; r < 4; r++) {
          float v = fmaxf(acc1[i][j][r] + bb, 0.f);
          ldsM[ka + i * 512 + (quad * 4 + r) * 8] = __float2bfloat16(v);
        }
    }
    // ---- GEMM2: acc2 += mid @ W2[:, c*128 .. +127]^T  (K-slice 128) ----
    for (int kt2 = 0; kt2 < 128; kt2 += 64) {
      const int p2 = kt2 >> 6;
#pragma unroll
      for (int hc = 0; hc < 2; hc++) {
        const __hip_bfloat16* wq0 = W2 + (size_t)(hc * 128 + ca) * 1024 + c * 128 + kt2 + kbase;
        const __hip_bfloat16* wq1 = wq0 + (size_t)64 * 1024;
        gld16(wq0,      ldsW + s0 * 512);
        gld16(wq0 + 32, ldsW + s0 * 512 + 4096);
        gld16(wq1,      ldsW + s0 * 512 + 2048);
        gld16(wq1 + 32, ldsW + s0 * 512 + 2048 + 4096);
        __syncthreads();
#pragma unroll
        for (int h = 0; h < 2; h++) {
          bf16x8 mf[4], bfr[2];
#pragma unroll
          for (int i = 0; i < 4; i++) mf[i] = *(const bf16x8*)(rM + p2 * 4096 + h * 2048 + i * 512);
#pragma unroll
          for (int j = 0; j < 2; j++) bfr[j] = *(const bf16x8*)(rB + h * 4096 + j * 512);
#pragma unroll
          for (int i = 0; i < 4; i++)
#pragma unroll
            for (int j = 0; j < 2; j++)
              acc2[i][hc * 2 + j] = __builtin_amdgcn_mfma_f32_16x16x32_bf16(mf[i], bfr[j], acc2[i][hc * 2 + j], 0, 0, 0);
        }
        __syncthreads();
      }
    }
  }

  // ---- EPI9-style epilogue: bias + resid(from ldsA) + round + LN -> out ----
  float* red  = (float*)ldsM;          // [64 rows] stride 9: {sum,sumsq} x 4 waves
  float* redm = (float*)ldsM + 600;    // [64 rows] x {mean, rstd}
  float bv9[4], gj[4], bj[4]; int cj9[4];
#pragma unroll
  for (int j = 0; j < 4; j++) {
    int hc = j >> 1, jj = j & 1;
    cj9[j] = hc * 128 + wv_ * 32 + jj * 16 + nl;
    bv9[j] = b2[cj9[j]];
    gj[j]  = lng[cj9[j]];
    bj[j]  = lnb[cj9[j]];
  }
#pragma unroll
  for (int i = 0; i < 4; i++) {
#pragma unroll
    for (int r = 0; r < 4; r++) {
      int row64 = i * 16 + quad * 4 + r;
      int m = bm + row64;
      if (m < NLQ) {
#pragma unroll
        for (int j = 0; j < 4; j++) {
          int k = cj9[j];
          // resid from resident A copy (bit-identical to h1 global read)
          int la = (k >> 6) * 4096 + ((k >> 5) & 1) * 2048 + i * 512
                 + ((k >> 3) & 3) * 128 + (quad * 4 + r) * 8 + (k & 7);
          float rv = b2f(ldsA[la]);
          float v = acc2[i][j][r] + bv9[j] + rv;
          acc2[i][j][r] = b2f(__float2bfloat16(v));
        }
      } else {
#pragma unroll
        for (int j = 0; j < 4; j++) acc2[i][j][r] = 0.f;
      }
      float s  = acc2[i][0][r] + acc2[i][1][r] + acc2[i][2][r] + acc2[i][3][r];
      float s2 = acc2[i][0][r]*acc2[i][0][r] + acc2[i][1][r]*acc2[i][1][r]
               + acc2[i][2][r]*acc2[i][2][r] + acc2[i][3][r]*acc2[i][3][r];
      s  += __shfl_xor(s, 1, 64);  s2 += __shfl_xor(s2, 1, 64);
      s  += __shfl_xor(s, 2, 64);  s2 += __shfl_xor(s2, 2, 64);
      s  += __shfl_xor(s, 4, 64);  s2 += __shfl_xor(s2, 4, 64);
      s  += __shfl_xor(s, 8, 64);  s2 += __shfl_xor(s2, 8, 64);
      if (nl == 0) { red[row64 * 9 + wv_ * 2] = s; red[row64 * 9 + wv_ * 2 + 1] = s2; }
    }
  }
  __syncthreads();
  if (t < 64) {
    float S = 0.f, S2 = 0.f;
#pragma unroll
    for (int w = 0; w < 4; w++) { S += red[t * 9 + w * 2]; S2 += red[t * 9 + w * 2 + 1]; }
    float mean = S * (1.f / 256.f);
    float var  = S2 * (1.f / 256.f) - mean * mean;
    redm[t * 2]     = mean;
    redm[t * 2 + 1] = rsqrtf(var + 1e-5f);
  }
  __syncthreads();
#pragma unroll
  for (int i = 0; i < 4; i++) {
#pragma unroll
    for (int r = 0; r < 4; r++) {
      int row64 = i * 16 + quad * 4 + r;
      int m = bm + row64;
      if (m >= NLQ) continue;
      float mean = redm[row64 * 2], rstd = redm[row64 * 2 + 1];
#pragma unroll
      for (int j = 0; j < 4; j++) {
        float o = (acc2[i][j][r] - mean) * rstd * gj[j] + bj[j];
        out[(size_t)m * 256 + cj9[j]] = __float2bfloat16(o);
      }
    }
  }
}

// ---------------------------------------------------------------------------
// table-driven 3-job GEMM (MT=64, FAST, bf16 W):
// EPI0 (input convs -> f32 rowmap) + fused GroupNorm raw-stat atomics
// EPI4 (output convs -> f32 NCHW) with LDS-transposed coalesced stores
// WITHCOPY: blocks >= gend do the lvl1 h2b->out f32 transpose copy.
// WITHC4:   blocks >= gend do conv4 (3x3 s2 on xt3, K=9216 split 32 chunks,
//           pre-transposed bf16 W, atomicAdd f32 into src rowmap).
// ---------------------------------------------------------------------------
struct GJob {
  const __hip_bfloat16* A; const __hip_bfloat16* W;
  const float* bias; float* out;
  int M, Nc, K, A_HW, A_L, A_off, O_HW, O_L, O_off, base, nbx;
};
struct GJobs { GJob j[3]; };

template<int EPI, bool WITHCOPY, bool WITHC4>
__global__ __launch_bounds__(256) void mgemm3_k(GJobs tab, int gend,
    const __hip_bfloat16* __restrict__ cpsrc, float* __restrict__ cpdst,
    const __hip_bfloat16* __restrict__ c4A, const __hip_bfloat16* __restrict__ c4W,
    float* __restrict__ c4out, float* __restrict__ stats)
{
  __shared__ char smem[24576];
  __hip_bfloat16* ldsA = (__hip_bfloat16*)smem;            // 8 KB
  __hip_bfloat16* ldsB = (__hip_bfloat16*)(smem + 8192);   // 16 KB
  const int t = threadIdx.x;
  const int b = blockIdx.x;

  if (WITHCOPY && b >= gend) {
    // lvl1 copy-out: h2b rows [10000,12500) bf16 -> out (N,256,50,50) f32
    int bb = b - gend;
    float (*tile)[33] = (float(*)[33])smem;
    int p0 = (bb % 79) * 32; int r = bb / 79; int c0 = (r & 7) * 32; int n = r >> 3;
    int tx = t & 31, ty = t >> 5;
    for (int i = ty; i < 32; i += 8) {
      int p = p0 + i, c = c0 + tx;
      tile[tx][i] = (p < 2500) ? b2f(cpsrc[((size_t)(n * LTOT + 10000 + p)) * 256 + c]) : 0.f;
    }
    __syncthreads();
    for (int i = ty; i < 32; i += 8) {
      int c = c0 + i, p = p0 + tx;
      if (p < 2500) cpdst[((size_t)n * 256 + c) * 2500 + p] = tile[i][tx];
    }
    return;
  }

  if (WITHC4 && b >= gend) {
    // conv4: M=98 rows, Nc=256, K=9216 in 32 chunks of 288. 2x2x32 = 128 blocks.
    int cb = b - gend;
    int kz = cb >> 2, bx2 = cb & 1, by2 = (cb >> 1) & 1;
    int bm = bx2 * 64, bn = by2 * 128;
    int k0 = kz * 288;
    const int sl = t & 63, mloc = sl & 15, kbase = (sl >> 4) * 8, s0 = t >> 6;
    int r0 = bm + s0 * 16 + mloc;
    bool av0 = r0 < 98;
    int g0n = 0, g0h = 0, g0w = 0;
    if (av0) { g0n = r0 / 49; int p = r0 - g0n * 49; g0h = p / 7; g0w = p - g0h * 7; }
    int nc0 = bn + s0 * 16 + mloc, nc1 = nc0 + 64;
    const __hip_bfloat16* wb0 = c4W + (size_t)nc0 * 9216;
    const __hip_bfloat16* wb1 = c4W + (size_t)nc1 * 9216;
    __hip_bfloat16* lwA0 = ldsA + s0 * 512 + sl * 8;
    __hip_bfloat16* lwB0 = ldsB + s0 * 512 + sl * 8;
    __hip_bfloat16* lwB1 = lwB0 + 2048;
    const int lane = t & 63, wvw = t >> 6;
    const __hip_bfloat16* rA = ldsA + lane * 8;
    const __hip_bfloat16* rB = ldsB + wvw * 1024 + lane * 8;
    const int colbase = bn + wvw * 32;
    f32x4 acc[4][2] = {};
    for (int kt = k0; kt < k0 + 288; kt += 32) {
      int kp = kt + kbase;
      {
        bf16x8 va0 = {};
        int rs = kp >> 10, c = kp & 1023;
        int rr = rs / 3, ss = rs - rr * 3;
        if (av0) { int ih = g0h*2-1+rr, iw = g0w*2-1+ss;
          if ((unsigned)ih < 13u && (unsigned)iw < 13u)
            va0 = *(const bf16x8*)(c4A + ((size_t)(g0n*169 + ih*13 + iw))*1024 + c); }
        *(bf16x8*)lwA0 = va0;
      }
      *(bf16x8*)lwB0 = *(const bf16x8*)(wb0 + kp);
      *(bf16x8*)lwB1 = *(const bf16x8*)(wb1 + kp);
      __syncthreads();
      bf16x8 af[4], bfr[2];
#pragma unroll
      for (int i = 0; i < 4; i++) af[i] = *(const bf16x8*)(rA + i * 512);
#pragma unroll
      for (int j2 = 0; j2 < 2; j2++) bfr[j2] = *(const bf16x8*)(rB + j2 * 512);
#pragma unroll
      for (int i = 0; i < 4; i++)
#pragma unroll
        for (int j2 = 0; j2 < 2; j2++)
          acc[i][j2] = __builtin_amdgcn_mfma_f32_16x16x32_bf16(af[i], bfr[j2], acc[i][j2], 0, 0, 0);
      __syncthreads();
    }
    const int quad = lane >> 4, nl = lane & 15;
#pragma unroll
    for (int i = 0; i < 4; i++) {
#pragma unroll
      for (int r = 0; r < 4; r++) {
        int m = bm + i * 16 + quad * 4 + r;
        if (m >= 98) continue;
        int n = m / 49, p = m - n * 49;
        size_t orow = (size_t)(n * LTOT + 13294 + p);
#pragma unroll
        for (int j2 = 0; j2 < 2; j2++)
          atomicAdd(c4out + orow * 256 + colbase + j2 * 16 + nl, acc[i][j2][r]);
      }
    }
    return;
  }

  const int j = (b >= tab.j[1].base) + (b >= tab.j[2].base);
  const GJob J = tab.j[j];
  const int local = b - J.base;
  const int bx = local % J.nbx, by = local / J.nbx;
  const int bm = bx * 64, bn = by * 128;

  const int sl = t & 63, mloc = sl & 15, kbase = (sl >> 4) * 8, s0 = t >> 6;
  const int r0 = bm + s0 * 16 + mloc;
  const int nc0 = bn + s0 * 16 + mloc, nc1 = nc0 + 64;

  const __hip_bfloat16* ap0 = J.A; bool av0 = false;
  if (r0 < J.M) { int nn = r0 / J.A_HW, p = r0 - nn * J.A_HW;
    ap0 = J.A + (size_t)(nn * J.A_L + J.A_off + p) * J.K + kbase; av0 = true; }
  const bool wv0 = nc0 < J.Nc, wv1 = nc1 < J.Nc;
  const __hip_bfloat16 *wb0 = J.W, *wb1 = J.W;
  if (wv0) wb0 = J.W + (size_t)nc0 * J.K + kbase;
  if (wv1) wb1 = J.W + (size_t)nc1 * J.K + kbase;

  __hip_bfloat16* lbA0 = ldsA + s0 * 512;
  __hip_bfloat16* lbB0 = ldsB + s0 * 512;
  __hip_bfloat16* lbB1 = lbB0 + 2048;
  const int lane = t & 63, wv_ = t >> 6;
  const __hip_bfloat16* rA = ldsA + lane * 8;
  const __hip_bfloat16* rB = ldsB + wv_ * 1024 + lane * 8;
  const int colbase = bn + wv_ * 32;

  f32x4 acc[4][2] = {};
  for (int kt = 0; kt < J.K; kt += 64) {
    if (av0) { gld16(ap0 + kt, lbA0); gld16(ap0 + kt + 32, lbA0 + 2048); }
    if (wv0) { gld16(wb0 + kt, lbB0); gld16(wb0 + kt + 32, lbB0 + 4096); }
    if (wv1) { gld16(wb1 + kt, lbB1); gld16(wb1 + kt + 32, lbB1 + 4096); }
    __syncthreads();
#pragma unroll
    for (int h = 0; h < 2; h++) {
      bf16x8 af[4], bfr[2];
#pragma unroll
      for (int i = 0; i < 4; i++) af[i] = *(const bf16x8*)(rA + h * 2048 + i * 512);
#pragma unroll
      for (int j2 = 0; j2 < 2; j2++) bfr[j2] = *(const bf16x8*)(rB + h * 4096 + j2 * 512);
#pragma unroll
      for (int i = 0; i < 4; i++)
#pragma unroll
        for (int j2 = 0; j2 < 2; j2++)
          acc[i][j2] = __builtin_amdgcn_mfma_f32_16x16x32_bf16(af[i], bfr[j2], acc[i][j2], 0, 0, 0);
    }
    __syncthreads();
  }

  const int quad = lane >> 4, nl = lane & 15;
  float bv[2]; int cj[2];
#pragma unroll
  for (int j2 = 0; j2 < 2; j2++) {
    cj[j2] = colbase + j2 * 16 + nl;
    bv[j2] = J.bias[cj[j2]];   // all cols valid: job grids exactly cover Nc
  }

  if constexpr (EPI == 0) {
    // rowmap store + fused GroupNorm raw-stat accumulation (li = job idx).
    // stats on the EXACT stored f32 values; order-only difference vs 2-pass.
    float sA[2] = {0.f, 0.f}, qA[2] = {0.f, 0.f};   // n=0 sum / sumsq per j2
    float sB[2] = {0.f, 0.f}, qB[2] = {0.f, 0.f};   // n=1
#pragma unroll
    for (int i = 0; i < 4; i++) {
#pragma unroll
      for (int r = 0; r < 4; r++) {
        int m = bm + i * 16 + quad * 4 + r;
        if (m >= J.M) continue;
        int n = m / J.O_HW, p = m - n * J.O_HW;
        size_t orow = (size_t)(n * J.O_L + J.O_off + p);
#pragma unroll
        for (int j2 = 0; j2 < 2; j2++) {
          float v = acc[i][j2][r] + bv[j2];
          J.out[orow * J.Nc + cj[j2]] = v;
          if (n == 0) { sA[j2] += v; qA[j2] += v * v; }
          else        { sB[j2] += v; qB[j2] += v * v; }
        }
      }
    }
    // reduce over all lanes sharing the same channel-group (nl bit3):
    // nl bits 0-2 (masks 1,2,4) and quad bits 4-5 (masks 16,32). Skip bit 3.
    // [R5 BUG: (8<<d) gave masks 64/128 -> self-wrap -> quarter-sampled stats]
    const int msks[5] = {1, 2, 4, 16, 32};
#pragma unroll
    for (int j2 = 0; j2 < 2; j2++) {
      float s0v = sA[j2], q0v = qA[j2], s1v = sB[j2], q1v = qB[j2];
#pragma unroll
      for (int d = 0; d < 5; d++) {
        int msk = msks[d];
        s0v += __shfl_xor(s0v, msk, 64);  q0v += __shfl_xor(q0v, msk, 64);
        s1v += __shfl_xor(s1v, msk, 64);  q1v += __shfl_xor(q1v, msk, 64);
      }
      if (lane == 0 || lane == 8) {
        int g = cj[j2] >> 3;
        if (s0v != 0.f || q0v != 0.f) {
          int si = (j * 2 + 0) * 32 + g;
          atomicAdd(&stats[si * 2], s0v);  atomicAdd(&stats[si * 2 + 1], q0v);
        }
        if (s1v != 0.f || q1v != 0.f) {
          int si = (j * 2 + 1) * 32 + g;
          atomicAdd(&stats[si * 2], s1v);  atomicAdd(&stats[si * 2 + 1], q1v);
        }
      }
    }
    return;
  }

  // EPI4: NCHW f32 output, coalesced via LDS transpose (64 p x 64 c halves).
  float* tbuf = (float*)smem;   // [64][65] f32 = 16.6 KB (aliases ldsA/ldsB, free now)
#pragma unroll
  for (int h2 = 0; h2 < 2; h2++) {
    __syncthreads();
    if ((wv_ >> 1) == h2) {
      int cbase = (wv_ & 1) * 32;
#pragma unroll
      for (int i = 0; i < 4; i++)
#pragma unroll
        for (int r = 0; r < 4; r++) {
          int pl = i * 16 + quad * 4 + r;
#pragma unroll
          for (int j2 = 0; j2 < 2; j2++)
            tbuf[pl * 65 + cbase + j2 * 16 + nl] = acc[i][j2][r] + bv[j2];
        }
    }
    __syncthreads();
#pragma unroll
    for (int kk = 0; kk < 16; kk++) {
      int idx = kk * 256 + t;
      int cl = idx >> 6, pl = idx & 63;       // wave -> channel, lanes -> p (contig)
      int m = bm + pl;
      if (m < J.M) {
        int n = m / J.O_HW, p = m - n * J.O_HW;
        J.out[((size_t)n * J.Nc + (bn + h2 * 64 + cl)) * J.O_HW + p] = tbuf[pl * 65 + cl];
      }
    }
  }
}

// flat bulk weight conversion + bias concat + stats zero + conv4 bias init
// + Wc4 pre-transpose to bf16 kp-order: wt4[nc][rs*1024+c] = Wc4[nc][c*9+rs]
// 1-D grid sized to exact work (7504 blocks) -- no empty-slice blocks.
#define CVT_T13 1632768
struct CvtEnt { const float* s; __hip_bfloat16* d; int n; int base; };
struct CvtTab { CvtEnt e[13]; };
__global__ __launch_bounds__(256) void cvt_weights_k(CvtTab tab,
    const float* __restrict__ bv, const float* __restrict__ bo,
    const float* __restrict__ ba, const float* __restrict__ br,
    float* __restrict__ catbias, float* __restrict__ stats,
    float* __restrict__ src, const float* __restrict__ bc4,
    const float* __restrict__ Wc4f, __hip_bfloat16* __restrict__ wt4)
{
  int i = blockIdx.x * 256 + threadIdx.x;
  if (i < CVT_T13) {
#pragma unroll
    for (int j = 12; j >= 0; j--) {
      if (i >= tab.e[j].base) {
        int k = i - tab.e[j].base;
        tab.e[j].d[k] = __float2bfloat16(tab.e[j].s[k]);
        return;
      }
    }
    return;
  }
  int i2 = i - CVT_T13;
  if (i2 < 1024) {
    if (i2 < 746) {
      float v;
      if (i2 < 256) v = bv[i2];
      else if (i2 < 576) v = bo[i2 - 256];
      else if (i2 < 736) v = ba[i2 - 576];
      else v = br[i2 - 736];
      catbias[i2] = v;
    }
    if (i2 < 512) stats[i2] = 0.f;
    return;
  }
  i2 -= 1024;
  if (i2 < 25088) {   // 98 rows x 256 ch: conv4 bias init
    int blk = i2 >> 8, c = i2 & 255;
    int n = blk / 49, p = blk - n * 49;
    src[((size_t)(n * LTOT + 13294 + p)) * 256 + c] = bc4[c];
    return;
  }
  i2 -= 25088;
  if (i2 < 262144) {   // 256 nc x 1024 c, 9 rs each (36B contiguous read/thread)
    int nc = i2 >> 10, c = i2 & 1023;
    const float* s = Wc4f + (size_t)nc * 9216 + (size_t)c * 9;
    __hip_bfloat16* d = wt4 + (size_t)nc * 9216 + c;
#pragma unroll
    for (int rs = 0; rs < 9; rs++) d[rs * 1024] = __float2bfloat16(s[rs]);
  }
}

// fused f32 NCHW -> bf16 channel-last for x0/x2/x3 + x1->srcb lvl1 (table-driven)
__global__ __launch_bounds__(256) void transpose_all_k(
    const float* __restrict__ x0, const float* __restrict__ x2,
    const float* __restrict__ x3, const float* __restrict__ x1,
    __hip_bfloat16* __restrict__ xt0, __hip_bfloat16* __restrict__ xt2,
    __hip_bfloat16* __restrict__ xt3, __hip_bfloat16* __restrict__ srcb)
{
  __shared__ float tile[32][33];
  int b = blockIdx.x;
  const float* x; __hip_bfloat16* xt; int C, HW, gx, gy, n, lvl1 = 0;
  if (b < 2504)      { x = x0; xt = xt0; C = 128;  HW = 10000; gx = b % 313; int r = b / 313; gy = r & 3; n = r >> 2; }
  else if (b < 3144) { int bb = b - 2504; x = x2; xt = xt2; C = 512;  HW = 625; gx = bb % 20; int r = bb / 20; gy = r & 15; n = r >> 4; }
  else if (b < 3528) { int bb = b - 3144; x = x3; xt = xt3; C = 1024; HW = 169; gx = bb % 6;  int r = bb / 6;  gy = r & 31; n = r >> 5; }
  else               { int bb = b - 3528; x = x1; xt = srcb; C = 256; HW = 2500; gx = bb % 79; int r = bb / 79; gy = r & 7; n = r >> 3; lvl1 = 1; }
  int p0 = gx * 32, c0 = gy * 32;
  const float* xb = x + (size_t)n * C * HW;
  __hip_bfloat16* xtb = lvl1 ? (srcb + ((size_t)(n * LTOT + 10000)) * 256)
                             : (xt + (size_t)n * HW * C);
  int tx = threadIdx.x & 31, ty = threadIdx.x >> 5;
  for (int i = ty; i < 32; i += 8) {
    int c = c0 + i, p = p0 + tx;
    tile[i][tx] = (p < HW) ? xb[(size_t)c * HW + p] : 0.f;
  }
  __syncthreads();
  for (int i = ty; i < 32; i += 8) {
    int p = p0 + i, c = c0 + tx;
    if (p < HW) xtb[(size_t)p * C + c] = __float2bfloat16(tile[tx][i]);
  }
}

// GroupNorm raw sums for conv4 level only (li=3; levels 0-2 fused in mgemm3)
__global__ __launch_bounds__(256) void gn_stats4_k(const float* __restrict__ src,
                                                   float* __restrict__ stats)
{
  int n = blockIdx.x, t = threadIdx.x;
  const float* base = src + ((size_t)(n * LTOT + 13294)) * 256 + t;
  float s = 0.f, s2 = 0.f;
  for (int r = 0; r < 49; r++) {
    float v = base[(size_t)r * 256];
    s += v; s2 += v * v;
  }
  s  += __shfl_down(s, 4, 64);  s2 += __shfl_down(s2, 4, 64);
  s  += __shfl_down(s, 2, 64);  s2 += __shfl_down(s2, 2, 64);
  s  += __shfl_down(s, 1, 64);  s2 += __shfl_down(s2, 1, 64);
  if ((t & 7) == 0) {
    int g = t >> 3;
    int si = (3 * 2 + n) * 32 + g;
    atomicAdd(&stats[si * 2],     s);
    atomicAdd(&stats[si * 2 + 1], s2);
  }
}

// merged GN apply + finalize -> bf16 only; grid 21686 blocks
__global__ __launch_bounds__(256) void gn_apply_k(const float* __restrict__ src,
    __hip_bfloat16* __restrict__ srcb,
    const float* __restrict__ stats, const float* __restrict__ g,
    const float* __restrict__ b)
{
  int x = blockIdx.x;
  int n = x / 10843, cidx = x - n * 10843;
  int li, off, hw, p;
  if (cidx < 10000)      { li = 0; off = 0;     hw = 10000; p = cidx; }
  else if (cidx < 10625) { li = 1; off = 12500; hw = 625;   p = cidx - 10000; }
  else if (cidx < 10794) { li = 2; off = 13125; hw = 169;   p = cidx - 10625; }
  else                   { li = 3; off = 13294; hw = 49;    p = cidx - 10794; }
  int t = threadIdx.x;
  int si = (li * 2 + n) * 32 + (t >> 3);
  float cnt = (float)(hw * 8);
  float mean = stats[si * 2] / cnt;
  float var = stats[si * 2 + 1] / cnt - mean * mean;
  float rstd = rsqrtf(var + 1e-5f);
  size_t a = ((size_t)(n * LTOT + off + p)) * 256 + t;
  float v = (src[a] - mean) * rstd * g[t] + b[t];
  srcb[a] = __float2bfloat16(v);
}

// ---------------------------------------------------------------------------
// deformable sampling v6b (PROVEN OPTIMUM — rounds 6/7/13 wider variants all
// lost to occupancy/conflict displacement): block = 2 queries; fused softmax;
// f16 value/off/aw; gather 2 ch/thread via dword load + packed f16 fma.
// LDS ~12 KB, VGPR 32, conflicts 0.
// [R1: 1-query-per-wave + dwordx2 halved MLP -> latency-bound, 83us. FAIL]
// [R2: saddr/readfirstlane gathers cut VALU 12% but exposed vmcnt stalls
//  (VALUBusy 83->65, dur 71.3->79.7us). The addr adds are free under load
//  latency. Do NOT restructure this gather; 71.3us is the local optimum.]
// ---------------------------------------------------------------------------
__global__ __launch_bounds__(256) void msdeform_k(const _Float16* __restrict__ value,
    const _Float16* __restrict__ offb, const _Float16* __restrict__ awb,
    const float* __restrict__ refb, __hip_bfloat16* __restrict__ out)
{
  __shared__ float s_awraw[320];
  __shared__ float s_ref[20];
  __shared__ float s_stat[32];
  __shared__ int4 s_cA[320];   // [ql*160 + h*20+pt] -> off00,w00p,off10,w10p
  __shared__ int4 s_cB[320];   //                     -> off01,w01p,off11,w11p
  const int t = threadIdx.x;
  const int q0 = blockIdx.x * 2;

  for (int i = t; i < 320; i += 256) {
    int ql = (i >= 160) ? 1 : 0;
    s_awraw[i] = (float)awb[(size_t)(q0 + ql) * 160 + (i - ql * 160)];
  }
  if (t < 20) {
    int ql = (t >= 10) ? 1 : 0;
    s_ref[t] = refb[(size_t)(q0 + ql) * 10 + (t - ql * 10)];
  }
  __syncthreads();

  if (t < 16) {
    const float* p = s_awraw + t * 20;
    float m = p[0];
#pragma unroll
    for (int j = 1; j < 20; j++) m = fmaxf(m, p[j]);
    float s = 0.f;
#pragma unroll
    for (int j = 0; j < 20; j++) s += expf(p[j] - m);
    s_stat[t * 2] = m;
    s_stat[t * 2 + 1] = 1.f / s;
  }
  __syncthreads();

  {
    const int Wl[5]   = {100, 50, 25, 13, 7};
    const int lvlo[5] = {0, 10000, 12500, 13125, 13294};
    for (int i = t; i < 320; i += 256) {
      int ql = (i >= 160) ? 1 : 0;
      int j = i - ql * 160;
      int h = j / 20, pt = j - h * 20;
      int l = pt >> 2;
      int q = q0 + ql;
      int W = Wl[l], lo = lvlo[l];
      float fW = (float)W;
      f16x2 o2h = *(const f16x2*)(offb + (size_t)q * 320 + j * 2);
      float ox = (float)o2h[0], oy = (float)o2h[1];
      int hs = (ql * 8 + h) * 2;
      float wgt = expf(s_awraw[i] - s_stat[hs]) * s_stat[hs + 1];
      float rx = s_ref[ql * 10 + l * 2], ry = s_ref[ql * 10 + l * 2 + 1];
      float x = (rx + ox / fW) * fW - 0.5f;
      float y = (ry + oy / fW) * fW - 0.5f;
      float x0f = floorf(x), y0f = floorf(y);
      float wx = x - x0f, wy = y - y0f;
      int x0 = (int)x0f, y0 = (int)y0f;
      int hb = h * 64;
      auto mk = [&](int ix, int iy, float w) {
        bool v = (ix >= 0) & (ix < W) & (iy >= 0) & (iy < W);
        int cx = min(max(ix, 0), W - 1), cy = min(max(iy, 0), W - 1);
        int off = (lo + cy * W + cx) * 512 + hb;
        float fw = v ? w * wgt : 0.f;
        unsigned hbits = (unsigned)__builtin_bit_cast(unsigned short, (_Float16)fw);
        return make_int2(off, (int)(hbits | (hbits << 16)));
      };
      int2 c00 = mk(x0,     y0,     (1.f - wx) * (1.f - wy));
      int2 c10 = mk(x0 + 1, y0,     wx * (1.f - wy));
      int2 c01 = mk(x0,     y0 + 1, (1.f - wx) * wy);
      int2 c11 = mk(x0 + 1, y0 + 1, wx * wy);
      s_cA[i] = make_int4(c00.x, c00.y, c10.x, c10.y);
      s_cB[i] = make_int4(c01.x, c01.y, c11.x, c11.y);
    }
  }
  __syncthreads();

  const int ql = t >> 7, h = (t >> 4) & 7, c2 = t & 15;
  const int q = q0 + ql;
  const int n = q / LTOT;
  const char* vb = (const char*)value + (size_t)n * LTOT * 512 + c2 * 4;
  f16x2 accA = {0, 0}, accB = {0, 0};
  const int bi = ql * 160 + h * 20;
#pragma unroll 5
  for (int p = 0; p < 20; p++) {
    int4 A = s_cA[bi + p];
    int4 B = s_cB[bi + p];
    {
      f16x2 v2 = __builtin_bit_cast(f16x2, *(const unsigned*)(vb + A.x));
      f16x2 w2 = __builtin_bit_cast(f16x2, (unsigned)A.y);
      accA = w2 * v2 + accA;
    }
    {
      f16x2 v2 = __builtin_bit_cast(f16x2, *(const unsigned*)(vb + A.z));
      f16x2 w2 = __builtin_bit_cast(f16x2, (unsigned)A.w);
      accB = w2 * v2 + accB;
    }
    {
      f16x2 v2 = __builtin_bit_cast(f16x2, *(const unsigned*)(vb + B.x));
      f16x2 w2 = __builtin_bit_cast(f16x2, (unsigned)B.y);
      accA = w2 * v2 + accA;
    }
    {
      f16x2 v2 = __builtin_bit_cast(f16x2, *(const unsigned*)(vb + B.z));
      f16x2 w2 = __builtin_bit_cast(f16x2, (unsigned)B.w);
      accB = w2 * v2 + accB;
    }
  }
  float a0 = (float)accA[0] + (float)accB[0];
  float a1 = (float)accA[1] + (float)accB[1];
  unsigned o0 = (unsigned)f2bu(a0);
  unsigned o1 = (unsigned)f2bu(a1);
  *(unsigned*)((char*)out + ((size_t)q * 256 + h * 32 + c2 * 2) * 2) = (o1 << 16) | o0;
}

extern "C" void kernel_launch(void* const* d_in, const int* in_sizes, int n_in,
                              void* d_out, int out_size, void* d_ws, size_t ws_size,
                              hipStream_t stream)
{
  const float* x0    = (const float*)d_in[0];
  const float* x1    = (const float*)d_in[1];
  const float* x2    = (const float*)d_in[2];
  const float* x3    = (const float*)d_in[3];
  const float* W_ref = (const float*)d_in[4];
  const float* b_ref = (const float*)d_in[5];
  const float* W_off = (const float*)d_in[6];
  const float* b_off = (const float*)d_in[7];
  const float* W_aw  = (const float*)d_in[8];
  const float* b_aw  = (const float*)d_in[9];
  const float* W_val = (const float*)d_in[10];
  const float* b_val = (const float*)d_in[11];
  const float* W_outp= (const float*)d_in[12];
  const float* b_outp= (const float*)d_in[13];
  const float* gn_g  = (const float*)d_in[14];
  const float* gn_b  = (const float*)d_in[15];
  const float* Wc1   = (const float*)d_in[16];
  const float* bc1   = (const float*)d_in[17];
  const float* Wc2   = (const float*)d_in[18];
  const float* bc2   = (const float*)d_in[19];
  const float* Wc3   = (const float*)d_in[20];
  const float* bc3   = (const float*)d_in[21];
  const float* Wc4   = (const float*)d_in[22];
  const float* bc4   = (const float*)d_in[23];
  const float* Wc11  = (const float*)d_in[24];
  const float* bc11  = (const float*)d_in[25];
  const float* Wc22  = (const float*)d_in[26];
  const float* bc22  = (const float*)d_in[27];
  const float* Wc33  = (const float*)d_in[28];
  const float* bc33  = (const float*)d_in[29];
  const float* ln1_g = (const float*)d_in[30];
  const float* ln1_b = (const float*)d_in[31];
  const float* W1    = (const float*)d_in[32];
  const float* b1f   = (const float*)d_in[33];
  const float* W2    = (const float*)d_in[34];
  const float* b2f_  = (const float*)d_in[35];
  const float* ln2_g = (const float*)d_in[36];
  const float* ln2_b = (const float*)d_in[37];

  // ---- workspace (byte offsets) ----
  char* wsb = (char*)d_ws;
  float* src             = (float*)(wsb + 0);
  _Float16* valb         = (_Float16*)(wsb + WS_VALB);
  __hip_bfloat16* h2b    = (__hip_bfloat16*)(wsb + 54652928);
  __hip_bfloat16* srcb   = (__hip_bfloat16*)(wsb + 81979392);
  __hip_bfloat16* h1b    = (__hip_bfloat16*)(wsb + 95642624);
  __hip_bfloat16* sampb  = (__hip_bfloat16*)(wsb + 109305856);
  _Float16* offbh        = (_Float16*)(wsb + WS_R);
  _Float16* awbh         = (_Float16*)(wsb + WS_AW);
  float* refb            = (float*)(wsb + WS_REF);
  __hip_bfloat16* xt0    = (__hip_bfloat16*)(wsb + WS_R);
  __hip_bfloat16* xt2    = (__hip_bfloat16*)(wsb + WS_R + 5120000);
  __hip_bfloat16* xt3    = (__hip_bfloat16*)(wsb + WS_R + 6400000);
  // conv4 pre-transposed W (4.7 MB): hole after xt3, before offb/midb written
  __hip_bfloat16* wWc4t  = (__hip_bfloat16*)(wsb + WS_R + 8388608);
  __hip_bfloat16* warena = (__hip_bfloat16*)(wsb + 177622016);
  float* stats           = (float*)(wsb + 180887552);
  float* catbias         = (float*)(wsb + 180889600);
  const size_t needed = 180892672;
  if (ws_size < needed) return;

  __hip_bfloat16* wWproj = warena + 0;
  __hip_bfloat16* wW_val = warena + 0;
  __hip_bfloat16* wW_off = warena + 65536;
  __hip_bfloat16* wW_aw  = warena + 147456;
  __hip_bfloat16* wW_ref = warena + 188416;
  __hip_bfloat16* wW_out = warena + 190976;
  __hip_bfloat16* wW1    = warena + 256512;
  __hip_bfloat16* wW2    = warena + 518656;
  __hip_bfloat16* wWc1   = warena + 780800;
  __hip_bfloat16* wWc2   = warena + 813568;
  __hip_bfloat16* wWc3   = warena + 944640;
  __hip_bfloat16* wWc11  = warena + 1206784;
  __hip_bfloat16* wWc22  = warena + 1239552;
  __hip_bfloat16* wWc33  = warena + 1370624;

  dim3 B(256);

  CvtTab tab = {{
    {W_val, wW_val, 65536, 0},       {W_off, wW_off, 81920, 65536},
    {W_aw,  wW_aw,  40960, 147456},  {W_ref, wW_ref, 2560,  188416},
    {W_outp,wW_out, 65536, 190976},  {W1,    wW1,  262144,  256512},
    {W2,    wW2,  262144,  518656},  {Wc1,   wWc1,  32768,  780800},
    {Wc2,   wWc2, 131072,  813568},  {Wc3,   wWc3, 262144,  944640},
    {Wc11,  wWc11, 32768, 1206784},  {Wc22,  wWc22,131072, 1239552},
    {Wc33,  wWc33,262144, 1370624}
  }};
  cvt_weights_k<<<7504,B,0,stream>>>(tab, b_val, b_off, b_aw, b_ref,
                                     catbias, stats, src, bc4, Wc4, wWc4t);

  // ---- phase 1: fused transposes (incl. x1->srcb lvl1), convs(+stats)+conv4, GN ----
  transpose_all_k<<<4792,B,0,stream>>>(x0, x2, x3, x1, xt0, xt2, xt3, srcb);

  GJobs injobs = {{
    { xt0, wWc1, bc1, src, 20000, 256, 128,  20000, 0, 0, 10000, LTOT, 0,     0,   313 },
    { xt2, wWc2, bc2, src, 1250,  256, 512,  1250,  0, 0, 625,   LTOT, 12500, 626, 20  },
    { xt3, wWc3, bc3, src, 338,   256, 1024, 338,   0, 0, 169,   LTOT, 13125, 666, 6   }
  }};
  mgemm3_k<0,false,true><<<806,B,0,stream>>>(injobs, 678, nullptr, nullptr,
                                             xt3, wWc4t, src, stats);
  gn_stats4_k<<<2,B,0,stream>>>(src, stats);
  gn_apply_k<<<21686,B,0,stream>>>(src, srcb, stats, gn_g, gn_b);

  // ---- fused projections + sampling ----
  mgemm_k<128,0,7,0><<<dim3(209,6),B,0,stream>>>(srcb, wWproj, catbias, d_ws, nullptr, nullptr, nullptr, NLQ,746,256,256, NLQ,0,0, NLQ,0,0);
  msdeform_k<<<13343,B,0,stream>>>(valb, offbh, awbh, refb, sampb);

  // ---- out-proj + resid(srcb) + LN1 fused (EPI9) -> h1b ----
  mgemm_k<64,0,9,0><<<dim3(417,1),B,0,stream>>>(sampb, wW_out, b_outp, h1b, srcb, ln1_g, ln1_b, NLQ,256,256,256, NLQ,0,0, NLQ,0,0);

  // ---- fused FFN v1 (64-row blocks, proven 461us total) -> h2b ----
  ffn_k<<<417,B,0,stream>>>(h1b, wW1, b1f, wW2, b2f_, ln2_g, ln2_b, h2b);

  // ---- output convs + lvl1 copy-out, single launch ----
  float* out = (float*)d_out;
  GJobs outjobs = {{
    { h2b, wWc11, bc11, out,           20000, 128,  256, 10000, LTOT, 0,     10000, 0, 0, 0,   313 },
    { h2b, wWc22, bc22, out + 3840000, 1250,  512,  256, 625,   LTOT, 12500, 625,   0, 0, 313, 20  },
    { h2b, wWc33, bc33, out + 4480000, 338,   1024, 256, 169,   LTOT, 13125, 169,   0, 0, 393, 6   }
  }};
  mgemm3_k<4,true,false><<<1705,B,0,stream>>>(outjobs, 441, h2b, out + 2560000,
                                              nullptr, nullptr, nullptr, nullptr);
}